// Round 13
// baseline (192.993 us; speedup 1.0000x reference)
//
#include <hip/hip_runtime.h>
#include <math.h>

// Problem constants
#define B_ 2
#define S_ 8193
#define L_ 8192
#define E_ 512
#define H_ 8
#define D_ 64
#define QKV_COLS 1536   // 3*E
#define SCALE 0.125f
#define M_ROWS 16386    // B*S
#define M_PAD 16512     // round up to 128 (out-proj GEMM)
#define M_PAD2 16640    // round up to 256 (qkv GEMM)

typedef unsigned short u16;
typedef __attribute__((ext_vector_type(8))) short bf16x8;
typedef __attribute__((ext_vector_type(8))) unsigned short u16x8;
typedef __attribute__((ext_vector_type(4))) float f32x4;

__device__ __forceinline__ u16 f2bf(float f) {
    unsigned u = __float_as_uint(f);
    unsigned r = (u + 0x7fffu + ((u >> 16) & 1u)) >> 16;   // RNE
    return (u16)r;
}
__device__ __forceinline__ float bf2f(u16 h) {
    return __uint_as_float((unsigned)h << 16);
}

__device__ __forceinline__ void gload_lds16(const void* g, void* l) {
    __builtin_amdgcn_global_load_lds(
        (const __attribute__((address_space(1))) void*)g,
        (__attribute__((address_space(3))) void*)l, 16, 0, 0);
}

#define WAITV8() asm volatile("s_waitcnt vmcnt(8)" ::: "memory")
#define WAITV4() asm volatile("s_waitcnt vmcnt(4)" ::: "memory")
#define WAITV2() asm volatile("s_waitcnt vmcnt(2)" ::: "memory")
#define WAITV0() asm volatile("s_waitcnt vmcnt(0)" ::: "memory")
#define LGKM0()  asm volatile("s_waitcnt lgkmcnt(0)" ::: "memory")
#define BAR()    __builtin_amdgcn_s_barrier()

// ---------------------------------------------------------------------------
// float -> bf16 conversion, 512 cols, zero-pads rows >= rows.
// ---------------------------------------------------------------------------
__global__ __launch_bounds__(256) void convert_bf16_512(
    const float* __restrict__ src, u16* __restrict__ dst, int rows, long total4)
{
    const long i = (long)blockIdx.x * 256 + threadIdx.x;
    if (i >= total4) return;
    const long f = i * 4;
    const long row = f >> 9;
    ushort4 o;
    if (row < rows) {
        const float4 v = *(const float4*)(src + f);
        o.x = f2bf(v.x); o.y = f2bf(v.y); o.z = f2bf(v.z); o.w = f2bf(v.w);
    } else {
        o = make_ushort4(0, 0, 0, 0);
    }
    *(ushort4*)(dst + f) = o;
}

// ---------------------------------------------------------------------------
// RoPE cos/sin table: tab[bl*32 + p2] = {cos, sin}
// ---------------------------------------------------------------------------
__global__ __launch_bounds__(256) void rope_table_kernel(
    const int* __restrict__ coords, float2* __restrict__ tab)
{
    const int i = blockIdx.x * 256 + threadIdx.x;   // bl*32 + p2
    const int p2 = i & 31;
    const int bl = i >> 5;
    const float coord = (float)coords[(size_t)bl * 2 + (p2 >> 4)] * 1e-5f;
    const float inv = exp2f(-0.83048202372184f * (float)(p2 & 15));
    float sn, cs;
    __sincosf(coord * inv, &sn, &cs);
    tab[i] = make_float2(cs, sn);
}

// ---------------------------------------------------------------------------
// QKV GEMM, 8-phase fine-interleave schedule (T3+T4+T5, m201-style):
// 256x256 tile, 8 waves (2Mx4N), BK=64, 2-buffer LDS (128 KB).
// Per K-tile: 4 quadrant-phases, each {wait; BAR; ds_read frags;
// 2x global_load_lds of next tile (need-ordered B0..B3,A0,A2,A1,A3);
// lgkmcnt(0)+sched_barrier; setprio(1); 16 MFMA; setprio(0)}.
// Counted vmcnt: vmcnt(2) before phase 0, vmcnt(4) before phase 2 —
// never drain-0 mid-loop. Chunk swizzle c^=(row&7) on src + read.
// K = 512 (8 tiles). Fused RoPE epilogue + LDS-staged coalesced C-write.
// A: M_PAD2 x 512 bf16 (zero-padded), W: 1536 x 512 bf16, C: bf16.
// ---------------------------------------------------------------------------
__global__ __launch_bounds__(512, 2) void gemm_qkv_8ph(
    const u16* __restrict__ A, const u16* __restrict__ W,
    const float* __restrict__ bias, u16* __restrict__ C,
    const float2* __restrict__ tab, int M)
{
    __shared__ __align__(16) u16 smem[65536];   // buf0: A@0 B@16384; buf1: A@32768 B@49152
    const int N = QKV_COLS;

    // XCD-aware bijective swizzle (m204)
    const int nwg = gridDim.x * gridDim.y;
    const int orig = blockIdx.y * gridDim.x + blockIdx.x;
    const int qq = nwg >> 3, rr = nwg & 7;
    const int xcd = orig & 7, off = orig >> 3;
    const int wgid = (xcd < rr ? xcd * (qq + 1) : rr * (qq + 1) + (xcd - rr) * qq) + off;
    const int m0 = (wgid / gridDim.x) * 256;
    const int n0 = (wgid % gridDim.x) * 256;

    const int tid  = threadIdx.x;
    const int wid  = tid >> 6;
    const int lane = tid & 63;
    const int wm = (wid >> 2) * 128;   // 2 M-waves
    const int wn = (wid & 3) * 64;     // 4 N-waves
    const int fr = lane & 15;
    const int fq = lane >> 4;          // 0..3

    const int srow = tid >> 3;         // 0..63: row within 64-row band
    const int sc   = tid & 7;          // 16B chunk
    const int swc  = sc ^ (srow & 7);  // swizzled source chunk

    f32x4 acc[8][4] = {};
    bf16x8 bfr[2][4];

    // stage one 64-row band (j) of A or B for tile at k-offset kn into buf base bb2
    #define STG_A(bb2, j, kn)                                                   \
        gload_lds16(A + (size_t)(m0 + (j) * 64 + srow) * 512 + (kn) + swc * 8,  \
                    smem + (bb2) + ((j) * 64 + srow) * 64 + sc * 8)
    #define STG_B(bb2, j, kn)                                                   \
        gload_lds16(W + (size_t)(n0 + (j) * 64 + srow) * 512 + (kn) + swc * 8,  \
                    smem + (bb2) + 16384 + ((j) * 64 + srow) * 64 + sc * 8)

    // one quadrant-phase: Q is a LITERAL 0..3 (acc indices must be static)
    #define PHASE(Q, t_, abase, bb2, kn1)                                       \
    do {                                                                        \
        if ((Q) == 0) { WAITV2(); }                                             \
        else if ((Q) == 2) { if ((t_) == 7) { WAITV0(); } else { WAITV4(); } }  \
        BAR();                                                                  \
        if ((Q) == 0) {                                                         \
            _Pragma("unroll")                                                   \
            for (int kk = 0; kk < 2; ++kk)                                      \
                _Pragma("unroll")                                               \
                for (int ni = 0; ni < 4; ++ni) {                                \
                    const int r_ = wn + ni * 16 + fr;                           \
                    bfr[kk][ni] = *(const bf16x8*)(smem + (abase) + 16384       \
                        + r_ * 64 + (((kk * 4 + fq) ^ (r_ & 7)) * 8));          \
                }                                                               \
        }                                                                       \
        bf16x8 afr[2][2];                                                       \
        _Pragma("unroll")                                                       \
        for (int kk = 0; kk < 2; ++kk)                                          \
            _Pragma("unroll")                                                   \
            for (int m2 = 0; m2 < 2; ++m2) {                                    \
                const int r_ = wm + ((Q) * 2 + m2) * 16 + fr;                   \
                afr[kk][m2] = *(const bf16x8*)(smem + (abase)                   \
                    + r_ * 64 + (((kk * 4 + fq) ^ (r_ & 7)) * 8));              \
            }                                                                   \
        if ((t_) < 7) {                                                         \
            if ((Q) == 0)      { STG_B(bb2, 0, kn1); STG_B(bb2, 1, kn1); }      \
            else if ((Q) == 1) { STG_B(bb2, 2, kn1); STG_B(bb2, 3, kn1); }      \
            else if ((Q) == 2) { STG_A(bb2, 0, kn1); STG_A(bb2, 2, kn1); }      \
            else               { STG_A(bb2, 1, kn1); STG_A(bb2, 3, kn1); }      \
        }                                                                       \
        LGKM0();                                                                \
        __builtin_amdgcn_sched_barrier(0);                                      \
        __builtin_amdgcn_s_setprio(1);                                          \
        _Pragma("unroll")                                                       \
        for (int m2 = 0; m2 < 2; ++m2)                                          \
            _Pragma("unroll")                                                   \
            for (int ni = 0; ni < 4; ++ni)                                      \
                _Pragma("unroll")                                               \
                for (int kk = 0; kk < 2; ++kk)                                  \
                    acc[(Q) * 2 + m2][ni] = __builtin_amdgcn_mfma_f32_16x16x32_bf16( \
                        afr[kk][m2], bfr[kk][ni], acc[(Q) * 2 + m2][ni], 0, 0, 0); \
        __builtin_amdgcn_s_setprio(0);                                          \
    } while (0)

    // prologue: tile 0 -> buf0, need-order B0..B3, A0, A2, A1, A3
    STG_B(0, 0, 0); STG_B(0, 1, 0); STG_B(0, 2, 0); STG_B(0, 3, 0);
    STG_A(0, 0, 0); STG_A(0, 2, 0); STG_A(0, 1, 0); STG_A(0, 3, 0);

    for (int t = 0; t < 8; ++t) {
        const int abase = (t & 1) << 15;         // *32768
        const int bb2   = ((t + 1) & 1) << 15;
        const int kn1   = (t + 1) * 64;
        PHASE(0, t, abase, bb2, kn1);
        PHASE(1, t, abase, bb2, kn1);
        PHASE(2, t, abase, bb2, kn1);
        PHASE(3, t, abase, bb2, kn1);
    }

    #undef PHASE
    #undef STG_A
    #undef STG_B

    __syncthreads();   // release LDS; reuse as 256x256 bf16 C staging

    u16* st = smem;
    const bool rope_blk = (n0 < 2 * E_);   // q or k column tiles
    #pragma unroll
    for (int mi = 0; mi < 8; ++mi) {
        #pragma unroll
        for (int j = 0; j < 4; ++j) {
            const int row = wm + mi * 16 + fq * 4 + j;
            const int gm = m0 + row;
            int b = 0, s = gm;
            if (gm >= S_) { b = 1; s = gm - S_; }
            const bool rot = rope_blk && (gm < M) && (s > 0);
            const float2* trow = tab + ((size_t)(b * L_ + (s - 1)) << 5);
            #pragma unroll
            for (int ni = 0; ni < 4; ++ni) {
                const int col = wn + ni * 16 + fr;
                const int gn = n0 + col;
                float v = acc[mi][ni][j] + bias[gn];
                const float partner = __shfl_xor(v, 1, 64);  // gn^1 lives in lane^1
                if (rot) {
                    const float2 tt = trow[(gn & 63) >> 1];
                    v = (gn & 1) ? (v * tt.x + partner * tt.y)
                                 : (v * tt.x - partner * tt.y);
                }
                st[row * 256 + col] = f2bf(v);
            }
        }
    }
    __syncthreads();
    #pragma unroll
    for (int i = 0; i < 16; ++i) {
        const int slot = i * 512 + tid;
        const int row = slot >> 5;
        const int ch = slot & 31;
        const int gm = m0 + row;
        if (gm < M)
            *(u16x8*)(C + (size_t)gm * N + n0 + ch * 8) =
                *(const u16x8*)(st + row * 256 + ch * 8);
    }
}

// ---------------------------------------------------------------------------
// Out-proj GEMM (fp32 out), 128x128 tile, depth-3 counted-vmcnt pipeline,
// single barrier per step, LDS-staged coalesced C-write. (R12, unchanged.)
// ---------------------------------------------------------------------------
__global__ __launch_bounds__(256) void gemm_out_128(
    const u16* __restrict__ A, const u16* __restrict__ W,
    const float* __restrict__ bias, float* __restrict__ C,
    int M, int N, int K)
{
    __shared__ __align__(16) u16 smem[32768];

    const int nwg = gridDim.x * gridDim.y;
    const int orig = blockIdx.y * gridDim.x + blockIdx.x;
    const int qq = nwg >> 3, rr = nwg & 7;
    const int xcd = orig & 7, off = orig >> 3;
    const int wgid = (xcd < rr ? xcd * (qq + 1) : rr * (qq + 1) + (xcd - rr) * qq) + off;
    const int m0 = (wgid / gridDim.x) * 128;
    const int n0 = (wgid % gridDim.x) * 128;

    const int tid  = threadIdx.x;
    const int wid  = tid >> 6;
    const int lane = tid & 63;
    const int wm = (wid >> 1) * 64;
    const int wn = (wid & 1) * 64;

    const int srow = lane >> 2;
    const int scol = ((lane & 3) ^ ((lane >> 3) & 3)) * 8;
    const int fr = lane & 15;
    const int fq = lane >> 4;
    const int sfq = (fq ^ ((fr >> 1) & 3)) * 8;

    const int c0 = wid * 2, c1 = wid * 2 + 1;
    const u16* ga0 = A + (size_t)(m0 + c0 * 16 + srow) * K + scol;
    const u16* ga1 = A + (size_t)(m0 + c1 * 16 + srow) * K + scol;
    const u16* gb0 = W + (size_t)(n0 + c0 * 16 + srow) * K + scol;
    const u16* gb1 = W + (size_t)(n0 + c1 * 16 + srow) * K + scol;
    const int la0 = c0 * 16 * 32, la1 = c1 * 16 * 32;

    f32x4 acc[4][4] = {};

    #define STAGE(bi, k0)                                       \
        do {                                                    \
            u16* as_ = smem + (bi) * 4096;                      \
            u16* bs_ = smem + 16384 + (bi) * 4096;              \
            gload_lds16(ga0 + (k0), as_ + la0);                 \
            gload_lds16(ga1 + (k0), as_ + la1);                 \
            gload_lds16(gb0 + (k0), bs_ + la0);                 \
            gload_lds16(gb1 + (k0), bs_ + la1);                 \
        } while (0)

    #define COMPUTE(bi)                                                          \
        do {                                                                     \
            const u16* as_ = smem + (bi) * 4096;                                 \
            const u16* bs_ = smem + 16384 + (bi) * 4096;                         \
            bf16x8 a[4], b[4];                                                   \
            _Pragma("unroll")                                                    \
            for (int mi = 0; mi < 4; ++mi)                                       \
                a[mi] = *(const bf16x8*)(as_ + (wm + mi * 16 + fr) * 32 + sfq);  \
            _Pragma("unroll")                                                    \
            for (int ni = 0; ni < 4; ++ni)                                       \
                b[ni] = *(const bf16x8*)(bs_ + (wn + ni * 16 + fr) * 32 + sfq);  \
            _Pragma("unroll")                                                    \
            for (int mi = 0; mi < 4; ++mi)                                       \
                _Pragma("unroll")                                                \
                for (int ni = 0; ni < 4; ++ni)                                   \
                    acc[mi][ni] = __builtin_amdgcn_mfma_f32_16x16x32_bf16(       \
                        a[mi], b[ni], acc[mi][ni], 0, 0, 0);                     \
        } while (0)

    const int nt = K / 32;

    STAGE(0, 0);
    STAGE(1, 32);
    STAGE(2, 64);

    int t = 0;
    for (; t <= nt - 4; ++t) {
        WAITV8(); BAR();
        COMPUTE(t & 3);
        STAGE((t + 3) & 3, (t + 3) * 32);
    }
    WAITV8(); BAR(); COMPUTE(t & 3); ++t;
    WAITV4(); BAR(); COMPUTE(t & 3); ++t;
    WAITV0(); BAR(); COMPUTE(t & 3);

    #undef STAGE
    #undef COMPUTE

    __syncthreads();

    float* stf = (float*)smem;           // 128 x 128 f32 = 64 KB
    #pragma unroll
    for (int mi = 0; mi < 4; ++mi)
        #pragma unroll
        for (int j = 0; j < 4; ++j) {
            const int r = wm + mi * 16 + fq * 4 + j;
            #pragma unroll
            for (int ni = 0; ni < 4; ++ni) {
                const int c = wn + ni * 16 + fr;
                stf[r * 128 + c] = acc[mi][ni][j] + bias[n0 + c];
            }
        }
    __syncthreads();
    #pragma unroll
    for (int i = 0; i < 16; ++i) {
        const int ch = i * 256 + tid;
        const int row = ch >> 5;
        const int coff = (ch & 31) * 4;
        const int gm = m0 + row;
        if (gm < M)
            *(float4*)(C + (size_t)gm * N + n0 + coff) =
                *(const float4*)(stf + row * 128 + coff);
    }
}

// ---------------------------------------------------------------------------
// CLS attention stage 1 (bf16 qkv): flash over S chunks.
// ---------------------------------------------------------------------------
#define NCHUNK 64
#define CLS_ROWS 129   // ceil(8193/64)

__global__ __launch_bounds__(256) void cls_attn_stage1(
    const u16* __restrict__ qkvb, float* __restrict__ part)
{
    const int blk = blockIdx.x;
    const int bh = blk >> 6, ch = blk & 63;
    const int b = bh >> 3, h = bh & 7;
    const int wid = threadIdx.x >> 6, lane = threadIdx.x & 63;
    const size_t base = (size_t)b * S_ * QKV_COLS;

    const float q = bf2f(qkvb[base + h * D_ + lane]);

    const int lo = ch * CLS_ROWS;
    const int hi = (lo + CLS_ROWS < S_) ? lo + CLS_ROWS : S_;

    float m = -1e30f, lsum = 0.f, acc = 0.f;
    for (int j = lo + wid; j < hi; j += 4) {
        const size_t roff = base + (size_t)j * QKV_COLS;
        float t = q * bf2f(qkvb[roff + E_ + h * D_ + lane]);
        #pragma unroll
        for (int o = 32; o; o >>= 1) t += __shfl_xor(t, o, 64);
        t *= SCALE;
        const float mn = fmaxf(m, t);
        const float corr = __expf(m - mn);
        const float p = __expf(t - mn);
        lsum = lsum * corr + p;
        acc = acc * corr + p * bf2f(qkvb[roff + 2 * E_ + h * D_ + lane]);
        m = mn;
    }

    __shared__ float sm[4], sl[4], sacc[4][64];
    if (lane == 0) { sm[wid] = m; sl[wid] = lsum; }
    sacc[wid][lane] = acc;
    __syncthreads();
    if (wid == 0) {
        const float gm = fmaxf(fmaxf(sm[0], sm[1]), fmaxf(sm[2], sm[3]));
        float gl = 0.f, ga = 0.f;
        #pragma unroll
        for (int w = 0; w < 4; ++w) {
            const float c = __expf(sm[w] - gm);
            gl += sl[w] * c;
            ga += sacc[w][lane] * c;
        }
        float* pp = part + ((size_t)bh * NCHUNK + ch) * 66;
        if (lane == 0) { pp[0] = gm; pp[1] = gl; }
        pp[2 + lane] = ga;
    }
}

__global__ __launch_bounds__(64) void cls_attn_stage2(
    const float* __restrict__ part, u16* __restrict__ attnb)
{
    const int bh = blockIdx.x;
    const int lane = threadIdx.x;
    const int b = bh >> 3, h = bh & 7;
    float gm = -1e30f;
    for (int c = 0; c < NCHUNK; ++c)
        gm = fmaxf(gm, part[((size_t)bh * NCHUNK + c) * 66]);
    float gl = 0.f, ga = 0.f;
    for (int c = 0; c < NCHUNK; ++c) {
        const float* pp = part + ((size_t)bh * NCHUNK + c) * 66;
        const float w = __expf(pp[0] - gm);
        gl += pp[1] * w;
        ga += pp[2 + lane] * w;
    }
    attnb[(size_t)(b * S_) * E_ + h * D_ + lane] = f2bf(ga / gl);
}

// ---------------------------------------------------------------------------
// Patch attention: lane = query. Block = 128 threads (2 waves) = 128 queries.
// K then V staged sequentially in one XOR-swizzled LDS buffer.
// ---------------------------------------------------------------------------
#define PQT 128

__global__ __launch_bounds__(128) void patch_attn(
    const u16* __restrict__ qkvb, u16* __restrict__ attnb)
{
    const int blk = blockIdx.x;
    const int qt = blk & 63;
    const int h = (blk >> 6) & 7;
    const int b = blk >> 9;
    const int l0 = qt * PQT;
    const size_t base = (size_t)b * S_ * QKV_COLS;
    const int hoff = h * D_;

    __shared__ u16 kv[144 * 64];
    __shared__ float kc[64], vc[64];

    const int t = threadIdx.x;

    if (t < 64) kc[t] = bf2f(qkvb[base + E_ + hoff + t]);
    else        vc[t - 64] = bf2f(qkvb[base + 2 * E_ + hoff + (t - 64)]);

    #pragma unroll
    for (int i = 0; i < 9; ++i) {
        const int ci = i * 128 + t;
        const int r = ci >> 3, c = ci & 7;
        const int lg = l0 - 8 + r;
        u16x8 v = {};
        if (lg >= 0 && lg < L_)
            v = *(const u16x8*)(qkvb + base + (size_t)(1 + lg) * QKV_COLS + E_ + hoff + c * 8);
        *(u16x8*)(kv + r * 64 + ((c ^ (r & 7)) * 8)) = v;
    }
    __syncthreads();

    const int l = l0 + t;
    const size_t qrow = base + (size_t)(1 + l) * QKV_COLS + hoff;

    float s[10];
    #pragma unroll
    for (int w = 0; w < 10; ++w) s[w] = 0.f;

    #pragma unroll
    for (int c = 0; c < 8; ++c) {
        const u16x8 qv = *(const u16x8*)(qkvb + qrow + c * 8);
        float qf[8];
        #pragma unroll
        for (int i = 0; i < 8; ++i) qf[i] = bf2f(qv[i]);
        #pragma unroll
        for (int i = 0; i < 8; ++i) s[0] += qf[i] * kc[c * 8 + i];
        #pragma unroll
        for (int w = 0; w < 9; ++w) {
            const int kr = t + 2 * w;
            const u16x8 kk = *(const u16x8*)(kv + kr * 64 + ((c ^ (kr & 7)) * 8));
            #pragma unroll
            for (int i = 0; i < 8; ++i) s[1 + w] += qf[i] * bf2f(kk[i]);
        }
    }

    s[0] *= SCALE;
    #pragma unroll
    for (int w = 0; w < 9; ++w) {
        const int lp = l + 2 * w - 8;
        s[1 + w] = (lp >= 0 && lp < L_) ? s[1 + w] * SCALE : -1e30f;
    }
    float m = s[0];
    #pragma unroll
    for (int w = 1; w < 10; ++w) m = fmaxf(m, s[w]);
    float sum = 0.f;
    #pragma unroll
    for (int w = 0; w < 10; ++w) { s[w] = __expf(s[w] - m); sum += s[w]; }
    const float rsum = 1.0f / sum;

    __syncthreads();
    #pragma unroll
    for (int i = 0; i < 9; ++i) {
        const int ci = i * 128 + t;
        const int r = ci >> 3, c = ci & 7;
        const int lg = l0 - 8 + r;
        u16x8 v = {};
        if (lg >= 0 && lg < L_)
            v = *(const u16x8*)(qkvb + base + (size_t)(1 + lg) * QKV_COLS + 2 * E_ + hoff + c * 8);
        *(u16x8*)(kv + r * 64 + ((c ^ (r & 7)) * 8)) = v;
    }
    __syncthreads();

    const size_t orow = (size_t)(b * S_ + 1 + l) * E_ + hoff;
    #pragma unroll
    for (int c = 0; c < 8; ++c) {
        float acc[8];
        #pragma unroll
        for (int i = 0; i < 8; ++i) acc[i] = s[0] * vc[c * 8 + i];
        #pragma unroll
        for (int w = 0; w < 9; ++w) {
            const int vr = t + 2 * w;
            const u16x8 vv = *(const u16x8*)(kv + vr * 64 + ((c ^ (vr & 7)) * 8));
            #pragma unroll
            for (int i = 0; i < 8; ++i) acc[i] += s[1 + w] * bf2f(vv[i]);
        }
        u16x8 o;
        #pragma unroll
        for (int i = 0; i < 8; ++i) o[i] = f2bf(acc[i] * rsum);
        *(u16x8*)(attnb + orow + c * 8) = o;
    }
}

// ---------------------------------------------------------------------------
// Launch
// ---------------------------------------------------------------------------
extern "C" void kernel_launch(void* const* d_in, const int* in_sizes, int n_in,
                              void* d_out, int out_size, void* d_ws, size_t ws_size,
                              hipStream_t stream)
{
    const float* x      = (const float*)d_in[0];
    const int*   coords = (const int*)  d_in[1];
    const float* w_qkv  = (const float*)d_in[2];
    const float* b_qkv  = (const float*)d_in[3];
    const float* w_out  = (const float*)d_in[4];
    const float* b_out  = (const float*)d_in[5];
    float* out = (float*)d_out;

    // workspace layout
    u16*   qkvb  = (u16*)d_ws;                                // M_ROWS x 1536 bf16
    u16*   attnb = qkvb + (size_t)M_ROWS * QKV_COLS;          // M_PAD x 512 bf16
    u16*   xb    = attnb + (size_t)M_PAD * E_;                // M_PAD2 x 512 bf16
    u16*   wqb   = xb + (size_t)M_PAD2 * E_;                  // 1536 x 512
    u16*   wob   = wqb + (size_t)QKV_COLS * E_;               // 512 x 512
    float* part  = (float*)(wob + (size_t)E_ * E_);           // 16*64*66 floats
    float2* tab  = (float2*)(part + (size_t)16 * NCHUNK * 66);// B*L*32 float2 (4 MB)

    // 1. convert x + weights to bf16, rope table, zero attnb pad rows
    {
        const long t4x = (long)M_PAD2 * E_ / 4;
        convert_bf16_512<<<(t4x + 255) / 256, 256, 0, stream>>>(x, xb, M_ROWS, t4x);
        const long t4q = (long)QKV_COLS * E_ / 4;
        convert_bf16_512<<<(t4q + 255) / 256, 256, 0, stream>>>(w_qkv, wqb, QKV_COLS, t4q);
        const long t4o = (long)E_ * E_ / 4;
        convert_bf16_512<<<(t4o + 255) / 256, 256, 0, stream>>>(w_out, wob, E_, t4o);
        rope_table_kernel<<<(B_ * L_ * 32) / 256, 256, 0, stream>>>(coords, tab);
        hipMemsetAsync(attnb + (size_t)M_ROWS * E_, 0,
                       (size_t)(M_PAD - M_ROWS) * E_ * sizeof(u16), stream);
    }

    // 2. QKV projection + fused RoPE, 8-phase 256x256 schedule
    {
        dim3 grid(QKV_COLS / 256, M_PAD2 / 256);   // 6 x 65
        gemm_qkv_8ph<<<grid, 512, 0, stream>>>(
            xb, wqb, b_qkv, qkvb, tab, M_ROWS);
    }

    // 3. CLS attention
    cls_attn_stage1<<<B_ * H_ * NCHUNK, 256, 0, stream>>>(qkvb, part);
    cls_attn_stage2<<<B_ * H_, 64, 0, stream>>>(part, attnb);

    // 4. Patch windowed attention
    patch_attn<<<B_ * H_ * (L_ / PQT), PQT, 0, stream>>>(qkvb, attnb);

    // 5. Output projection (fp32 out)
    {
        dim3 grid(E_ / 128, M_PAD / 128);
        gemm_out_128<<<grid, 256, 0, stream>>>(
            attnb, wob, b_out, out, M_ROWS, E_, E_);
    }
}

// Round 14
// 154.419 us; speedup vs baseline: 1.2498x; 1.2498x over previous
//
#include <hip/hip_runtime.h>
#include <math.h>

// Problem constants
#define B_ 2
#define S_ 8193
#define L_ 8192
#define E_ 512
#define H_ 8
#define D_ 64
#define QKV_COLS 1536   // 3*E
#define SCALE 0.125f
#define M_ROWS 16386    // B*S
#define M_PAD 16512     // round up to 128

typedef unsigned short u16;
typedef __attribute__((ext_vector_type(8))) short bf16x8;
typedef __attribute__((ext_vector_type(8))) unsigned short u16x8;
typedef __attribute__((ext_vector_type(4))) float f32x4;

__device__ __forceinline__ u16 f2bf(float f) {
    unsigned u = __float_as_uint(f);
    unsigned r = (u + 0x7fffu + ((u >> 16) & 1u)) >> 16;   // RNE
    return (u16)r;
}
__device__ __forceinline__ float bf2f(u16 h) {
    return __uint_as_float((unsigned)h << 16);
}

__device__ __forceinline__ void gload_lds16(const void* g, void* l) {
    __builtin_amdgcn_global_load_lds(
        (const __attribute__((address_space(1))) void*)g,
        (__attribute__((address_space(3))) void*)l, 16, 0, 0);
}

#define WAITV8() asm volatile("s_waitcnt vmcnt(8)" ::: "memory")
#define WAITV4() asm volatile("s_waitcnt vmcnt(4)" ::: "memory")
#define WAITV0() asm volatile("s_waitcnt vmcnt(0)" ::: "memory")
#define LGKM0()  asm volatile("s_waitcnt lgkmcnt(0)" ::: "memory")
#define BAR()    __builtin_amdgcn_s_barrier()

// ---------------------------------------------------------------------------
// Fused prep: wqb convert | wob convert | rope table | attnb pad zero.
// One grid-stride-free flat launch covering all four ranges.
// ---------------------------------------------------------------------------
#define PREP_W1 (QKV_COLS * E_ / 4)            // 196608 w_qkv quads
#define PREP_W2 (E_ * E_ / 4)                  // 65536 w_out quads
#define PREP_W3 (B_ * L_ * 32)                 // 524288 rope entries
#define PREP_W4 ((M_PAD - M_ROWS) * E_ / 8)    // 8064 pad chunks
#define PREP_TOTAL (PREP_W1 + PREP_W2 + PREP_W3 + PREP_W4)

__global__ __launch_bounds__(256) void prep_kernel(
    const float* __restrict__ w_qkv, const float* __restrict__ w_out,
    const int* __restrict__ coords,
    u16* __restrict__ wqb, u16* __restrict__ wob,
    float2* __restrict__ tab, u16* __restrict__ attnb)
{
    long i = (long)blockIdx.x * 256 + threadIdx.x;
    if (i < PREP_W1) {
        const float4 v = *(const float4*)(w_qkv + i * 4);
        ushort4 o = { f2bf(v.x), f2bf(v.y), f2bf(v.z), f2bf(v.w) };
        *(ushort4*)(wqb + i * 4) = o;
        return;
    }
    i -= PREP_W1;
    if (i < PREP_W2) {
        const float4 v = *(const float4*)(w_out + i * 4);
        ushort4 o = { f2bf(v.x), f2bf(v.y), f2bf(v.z), f2bf(v.w) };
        *(ushort4*)(wob + i * 4) = o;
        return;
    }
    i -= PREP_W2;
    if (i < PREP_W3) {
        const int p2 = (int)i & 31;
        const int bl = (int)i >> 5;
        const float coord = (float)coords[(size_t)bl * 2 + (p2 >> 4)] * 1e-5f;
        const float inv = exp2f(-0.83048202372184f * (float)(p2 & 15));
        float sn, cs;
        __sincosf(coord * inv, &sn, &cs);
        tab[i] = make_float2(cs, sn);
        return;
    }
    i -= PREP_W3;
    if (i < PREP_W4) {
        u16x8 z = {};
        *(u16x8*)(attnb + (size_t)M_ROWS * E_ + i * 8) = z;
    }
}

// ---------------------------------------------------------------------------
// QKV GEMM with fused fp32->bf16 A-staging (reg-staged) + fused RoPE.
// C = bf16( RoPE( X @ W^T + bias ) ).  X fp32 M x K, W bf16 N x K.
// 128x128 tile, BK=32, 4 waves. Depth-2 rings, one barrier per step.
// (R12 best variant, verbatim.)
// ---------------------------------------------------------------------------
__global__ __launch_bounds__(256) void gemm_qkv_fused(
    const float* __restrict__ X, const u16* __restrict__ W,
    const float* __restrict__ bias, u16* __restrict__ C,
    const float2* __restrict__ tab, int M, int N, int K)
{
    __shared__ __align__(16) u16 smem[16384];   // As0 As1 Bs0 Bs1 (8 KB each)

    const int nwg = gridDim.x * gridDim.y;
    const int orig = blockIdx.y * gridDim.x + blockIdx.x;
    const int qq = nwg >> 3, rr = nwg & 7;
    const int xcd = orig & 7, off = orig >> 3;
    const int wgid = (xcd < rr ? xcd * (qq + 1) : rr * (qq + 1) + (xcd - rr) * qq) + off;
    const int m0 = (wgid / gridDim.x) * 128;
    const int n0 = (wgid % gridDim.x) * 128;

    const int tid  = threadIdx.x;
    const int wid  = tid >> 6;
    const int lane = tid & 63;
    const int wm = (wid >> 1) * 64;
    const int wn = (wid & 1) * 64;
    const int fr = lane & 15;
    const int fq = lane >> 4;
    const int sfq = (fq ^ ((fr >> 1) & 3)) * 8;

    const int r0 = tid >> 3;
    const int c4 = tid & 7;
    const int aoff = r0 * 32 + (((c4 >> 1) ^ ((r0 >> 1) & 3)) * 8) + (c4 & 1) * 4;

    const int srow = lane >> 2;
    const int scol = ((lane & 3) ^ ((lane >> 3) & 3)) * 8;
    const int c0 = wid * 2, c1 = wid * 2 + 1;
    const u16* gb0 = W + (size_t)(n0 + c0 * 16 + srow) * K + scol;
    const u16* gb1 = W + (size_t)(n0 + c1 * 16 + srow) * K + scol;
    const int lb0 = c0 * 16 * 32, lb1 = c1 * 16 * 32;

    float4 ra[4];
    f32x4 acc[4][4] = {};

    #define ALOAD(k0)                                                           \
        do {                                                                    \
            _Pragma("unroll")                                                   \
            for (int i = 0; i < 4; ++i) {                                       \
                const int gm = m0 + r0 + 32 * i;                                \
                ra[i] = (gm < M)                                                \
                    ? *(const float4*)(X + (size_t)gm * K + (k0) + c4 * 4)      \
                    : make_float4(0.f, 0.f, 0.f, 0.f);                          \
            }                                                                   \
        } while (0)

    #define ADSW(buf)                                                           \
        do {                                                                    \
            u16* as_ = smem + (buf) * 4096;                                     \
            _Pragma("unroll")                                                   \
            for (int i = 0; i < 4; ++i) {                                       \
                ushort4 o;                                                      \
                o.x = f2bf(ra[i].x); o.y = f2bf(ra[i].y);                       \
                o.z = f2bf(ra[i].z); o.w = f2bf(ra[i].w);                       \
                *(ushort4*)(as_ + aoff + 1024 * i) = o;                         \
            }                                                                   \
        } while (0)

    #define WSTAGE(buf, k0)                                                     \
        do {                                                                    \
            u16* bs_ = smem + 8192 + (buf) * 4096;                              \
            gload_lds16(gb0 + (k0), bs_ + lb0);                                 \
            gload_lds16(gb1 + (k0), bs_ + lb1);                                 \
        } while (0)

    #define COMPUTE(buf)                                                         \
        do {                                                                     \
            const u16* as_ = smem + (buf) * 4096;                                \
            const u16* bs_ = smem + 8192 + (buf) * 4096;                         \
            bf16x8 a[4], b[4];                                                   \
            _Pragma("unroll")                                                    \
            for (int mi = 0; mi < 4; ++mi)                                       \
                a[mi] = *(const bf16x8*)(as_ + (wm + mi * 16 + fr) * 32 + sfq);  \
            _Pragma("unroll")                                                    \
            for (int ni = 0; ni < 4; ++ni)                                       \
                b[ni] = *(const bf16x8*)(bs_ + (wn + ni * 16 + fr) * 32 + sfq);  \
            _Pragma("unroll")                                                    \
            for (int mi = 0; mi < 4; ++mi)                                       \
                _Pragma("unroll")                                                \
                for (int ni = 0; ni < 4; ++ni)                                   \
                    acc[mi][ni] = __builtin_amdgcn_mfma_f32_16x16x32_bf16(       \
                        a[mi], b[ni], acc[mi][ni], 0, 0, 0);                     \
        } while (0)

    const int nt = K / 32;   // 16

    ALOAD(0); WSTAGE(0, 0);
    WAITV0();
    ADSW(0);
    ALOAD(32); WSTAGE(1, 32);
    LGKM0(); BAR();

    for (int t = 0; t < nt; ++t) {
        COMPUTE(t & 1);
        if (t + 1 < nt) {
            WAITV0();
            ADSW((t + 1) & 1);
            if (t + 2 < nt) ALOAD((t + 2) * 32);
            LGKM0(); BAR();
            if (t + 2 < nt) WSTAGE(t & 1, (t + 2) * 32);
        }
    }

    #undef ALOAD
    #undef ADSW
    #undef WSTAGE
    #undef COMPUTE

    __syncthreads();

    u16* st = smem;                           // 128 x 128 bf16 = 32 KB
    const bool rope_blk = (n0 < 2 * E_);
    #pragma unroll
    for (int mi = 0; mi < 4; ++mi) {
        #pragma unroll
        for (int j = 0; j < 4; ++j) {
            const int row = wm + mi * 16 + fq * 4 + j;
            const int gm = m0 + row;
            int b = 0, s = gm;
            if (gm >= S_) { b = 1; s = gm - S_; }
            const bool rot = rope_blk && (gm < M) && (s > 0);
            const float2* trow = tab + ((size_t)(b * L_ + (s - 1)) << 5);
            #pragma unroll
            for (int ni = 0; ni < 4; ++ni) {
                const int col = wn + ni * 16 + fr;
                const int gn = n0 + col;
                float v = acc[mi][ni][j] + bias[gn];
                const float partner = __shfl_xor(v, 1, 64);
                if (rot) {
                    const float2 tt = trow[(gn & 63) >> 1];
                    v = (gn & 1) ? (v * tt.x + partner * tt.y)
                                 : (v * tt.x - partner * tt.y);
                }
                st[row * 128 + col] = f2bf(v);
            }
        }
    }
    __syncthreads();
    #pragma unroll
    for (int i = 0; i < 8; ++i) {
        const int ch = i * 256 + tid;
        const int row = ch >> 4;
        const int coff = (ch & 15) * 8;
        const int gm = m0 + row;
        if (gm < M)
            *(u16x8*)(C + (size_t)gm * N + n0 + coff) =
                *(const u16x8*)(st + row * 128 + coff);
    }
}

// ---------------------------------------------------------------------------
// Out-proj GEMM (fp32 out), 128x128 tile, depth-3 counted-vmcnt pipeline,
// LDS-staged coalesced C-write. (R12, unchanged.)
// ---------------------------------------------------------------------------
__global__ __launch_bounds__(256) void gemm_out_128(
    const u16* __restrict__ A, const u16* __restrict__ W,
    const float* __restrict__ bias, float* __restrict__ C,
    int M, int N, int K)
{
    __shared__ __align__(16) u16 smem[32768];

    const int nwg = gridDim.x * gridDim.y;
    const int orig = blockIdx.y * gridDim.x + blockIdx.x;
    const int qq = nwg >> 3, rr = nwg & 7;
    const int xcd = orig & 7, off = orig >> 3;
    const int wgid = (xcd < rr ? xcd * (qq + 1) : rr * (qq + 1) + (xcd - rr) * qq) + off;
    const int m0 = (wgid / gridDim.x) * 128;
    const int n0 = (wgid % gridDim.x) * 128;

    const int tid  = threadIdx.x;
    const int wid  = tid >> 6;
    const int lane = tid & 63;
    const int wm = (wid >> 1) * 64;
    const int wn = (wid & 1) * 64;

    const int srow = lane >> 2;
    const int scol = ((lane & 3) ^ ((lane >> 3) & 3)) * 8;
    const int fr = lane & 15;
    const int fq = lane >> 4;
    const int sfq = (fq ^ ((fr >> 1) & 3)) * 8;

    const int c0 = wid * 2, c1 = wid * 2 + 1;
    const u16* ga0 = A + (size_t)(m0 + c0 * 16 + srow) * K + scol;
    const u16* ga1 = A + (size_t)(m0 + c1 * 16 + srow) * K + scol;
    const u16* gb0 = W + (size_t)(n0 + c0 * 16 + srow) * K + scol;
    const u16* gb1 = W + (size_t)(n0 + c1 * 16 + srow) * K + scol;
    const int la0 = c0 * 16 * 32, la1 = c1 * 16 * 32;

    f32x4 acc[4][4] = {};

    #define STAGE(bi, k0)                                       \
        do {                                                    \
            u16* as_ = smem + (bi) * 4096;                      \
            u16* bs_ = smem + 16384 + (bi) * 4096;              \
            gload_lds16(ga0 + (k0), as_ + la0);                 \
            gload_lds16(ga1 + (k0), as_ + la1);                 \
            gload_lds16(gb0 + (k0), bs_ + la0);                 \
            gload_lds16(gb1 + (k0), bs_ + la1);                 \
        } while (0)

    #define COMPUTE(bi)                                                          \
        do {                                                                     \
            const u16* as_ = smem + (bi) * 4096;                                 \
            const u16* bs_ = smem + 16384 + (bi) * 4096;                         \
            bf16x8 a[4], b[4];                                                   \
            _Pragma("unroll")                                                    \
            for (int mi = 0; mi < 4; ++mi)                                       \
                a[mi] = *(const bf16x8*)(as_ + (wm + mi * 16 + fr) * 32 + sfq);  \
            _Pragma("unroll")                                                    \
            for (int ni = 0; ni < 4; ++ni)                                       \
                b[ni] = *(const bf16x8*)(bs_ + (wn + ni * 16 + fr) * 32 + sfq);  \
            _Pragma("unroll")                                                    \
            for (int mi = 0; mi < 4; ++mi)                                       \
                _Pragma("unroll")                                                \
                for (int ni = 0; ni < 4; ++ni)                                   \
                    acc[mi][ni] = __builtin_amdgcn_mfma_f32_16x16x32_bf16(       \
                        a[mi], b[ni], acc[mi][ni], 0, 0, 0);                     \
        } while (0)

    const int nt = K / 32;

    STAGE(0, 0);
    STAGE(1, 32);
    STAGE(2, 64);

    int t = 0;
    for (; t <= nt - 4; ++t) {
        WAITV8(); BAR();
        COMPUTE(t & 3);
        STAGE((t + 3) & 3, (t + 3) * 32);
    }
    WAITV8(); BAR(); COMPUTE(t & 3); ++t;
    WAITV4(); BAR(); COMPUTE(t & 3); ++t;
    WAITV0(); BAR(); COMPUTE(t & 3);

    #undef STAGE
    #undef COMPUTE

    __syncthreads();

    float* stf = (float*)smem;
    #pragma unroll
    for (int mi = 0; mi < 4; ++mi)
        #pragma unroll
        for (int j = 0; j < 4; ++j) {
            const int r = wm + mi * 16 + fq * 4 + j;
            #pragma unroll
            for (int ni = 0; ni < 4; ++ni) {
                const int c = wn + ni * 16 + fr;
                stf[r * 128 + c] = acc[mi][ni][j] + bias[n0 + c];
            }
        }
    __syncthreads();
    #pragma unroll
    for (int i = 0; i < 16; ++i) {
        const int ch = i * 256 + tid;
        const int row = ch >> 5;
        const int coff = (ch & 31) * 4;
        const int gm = m0 + row;
        if (gm < M)
            *(float4*)(C + (size_t)gm * N + n0 + coff) =
                *(const float4*)(stf + row * 128 + coff);
    }
}

// ---------------------------------------------------------------------------
// Merged attention: blocks [0, 1024) = cls stage 1; [1024, 1536) = patch.
// Both read qkvb; outputs disjoint. 256 threads.
// Patch: 256 queries/block, 272-row K/V window staged in swizzled LDS.
// ---------------------------------------------------------------------------
#define NCHUNK 64
#define CLS_ROWS 129             // ceil(8193/64)
#define CLS_BLOCKS (B_ * H_ * NCHUNK)   // 1024
#define PQT 256
#define PATCH_BLOCKS (B_ * H_ * (L_ / PQT))  // 512

__global__ __launch_bounds__(256) void attn_fused(
    const u16* __restrict__ qkvb, float* __restrict__ part,
    u16* __restrict__ attnb)
{
    __shared__ __align__(16) u16 sbuf[272 * 64];   // patch K/V window (34.8 KB)
    __shared__ float kcvc[128];
    __shared__ float sm4[4], sl4[4];

    const int blk = blockIdx.x;

    if (blk < CLS_BLOCKS) {
        // ---------------- CLS stage 1 ----------------
        const int bh = blk >> 6, ch = blk & 63;
        const int b = bh >> 3, h = bh & 7;
        const int wid = threadIdx.x >> 6, lane = threadIdx.x & 63;
        const size_t base = (size_t)b * S_ * QKV_COLS;

        const float q = bf2f(qkvb[base + h * D_ + lane]);

        const int lo = ch * CLS_ROWS;
        const int hi = (lo + CLS_ROWS < S_) ? lo + CLS_ROWS : S_;

        float m = -1e30f, lsum = 0.f, acc = 0.f;
        for (int j = lo + wid; j < hi; j += 4) {
            const size_t roff = base + (size_t)j * QKV_COLS;
            float t = q * bf2f(qkvb[roff + E_ + h * D_ + lane]);
            #pragma unroll
            for (int o = 32; o; o >>= 1) t += __shfl_xor(t, o, 64);
            t *= SCALE;
            const float mn = fmaxf(m, t);
            const float corr = __expf(m - mn);
            const float p = __expf(t - mn);
            lsum = lsum * corr + p;
            acc = acc * corr + p * bf2f(qkvb[roff + 2 * E_ + h * D_ + lane]);
            m = mn;
        }

        float* sacc = (float*)sbuf;   // 4 x 64 floats
        if (lane == 0) { sm4[wid] = m; sl4[wid] = lsum; }
        sacc[wid * 64 + lane] = acc;
        __syncthreads();
        if (wid == 0) {
            const float gm = fmaxf(fmaxf(sm4[0], sm4[1]), fmaxf(sm4[2], sm4[3]));
            float gl = 0.f, ga = 0.f;
            #pragma unroll
            for (int w = 0; w < 4; ++w) {
                const float c = __expf(sm4[w] - gm);
                gl += sl4[w] * c;
                ga += sacc[w * 64 + lane] * c;
            }
            float* pp = part + ((size_t)bh * NCHUNK + ch) * 66;
            if (lane == 0) { pp[0] = gm; pp[1] = gl; }
            pp[2 + lane] = ga;
        }
        return;
    }

    // ---------------- patch attention ----------------
    const int pblk = blk - CLS_BLOCKS;
    const int qt = pblk & 31;              // 32 tiles
    const int h = (pblk >> 5) & 7;
    const int b = pblk >> 8;
    const int l0 = qt * PQT;
    const size_t base = (size_t)b * S_ * QKV_COLS;
    const int hoff = h * D_;

    u16* kv = sbuf;
    float* kc = kcvc;
    float* vc = kcvc + 64;

    const int t = threadIdx.x;

    if (t < 64) kc[t] = bf2f(qkvb[base + E_ + hoff + t]);
    else if (t < 128) vc[t - 64] = bf2f(qkvb[base + 2 * E_ + hoff + (t - 64)]);

    // stage K rows l0-8 .. l0+263 (272 rows x 8 chunks = 2176 slots)
    #pragma unroll
    for (int i = 0; i < 9; ++i) {
        const int s = i * 256 + t;
        if (s < 272 * 8) {
            const int r = s >> 3, c = s & 7;
            const int lg = l0 - 8 + r;
            u16x8 v = {};
            if (lg >= 0 && lg < L_)
                v = *(const u16x8*)(qkvb + base + (size_t)(1 + lg) * QKV_COLS + E_ + hoff + c * 8);
            *(u16x8*)(kv + r * 64 + ((c ^ (r & 7)) * 8)) = v;
        }
    }
    __syncthreads();

    const int l = l0 + t;
    const size_t qrow = base + (size_t)(1 + l) * QKV_COLS + hoff;

    float s[10];
    #pragma unroll
    for (int w = 0; w < 10; ++w) s[w] = 0.f;

    #pragma unroll
    for (int c = 0; c < 8; ++c) {
        const u16x8 qv = *(const u16x8*)(qkvb + qrow + c * 8);
        float qf[8];
        #pragma unroll
        for (int i = 0; i < 8; ++i) qf[i] = bf2f(qv[i]);
        #pragma unroll
        for (int i = 0; i < 8; ++i) s[0] += qf[i] * kc[c * 8 + i];
        #pragma unroll
        for (int w = 0; w < 9; ++w) {
            const int kr = t + 2 * w;
            const u16x8 kk = *(const u16x8*)(kv + kr * 64 + ((c ^ (kr & 7)) * 8));
            #pragma unroll
            for (int i = 0; i < 8; ++i) s[1 + w] += qf[i] * bf2f(kk[i]);
        }
    }

    s[0] *= SCALE;
    #pragma unroll
    for (int w = 0; w < 9; ++w) {
        const int lp = l + 2 * w - 8;
        s[1 + w] = (lp >= 0 && lp < L_) ? s[1 + w] * SCALE : -1e30f;
    }
    float m = s[0];
    #pragma unroll
    for (int w = 1; w < 10; ++w) m = fmaxf(m, s[w]);
    float sum = 0.f;
    #pragma unroll
    for (int w = 0; w < 10; ++w) { s[w] = __expf(s[w] - m); sum += s[w]; }
    const float rsum = 1.0f / sum;

    // restage V over K
    __syncthreads();
    #pragma unroll
    for (int i = 0; i < 9; ++i) {
        const int sl = i * 256 + t;
        if (sl < 272 * 8) {
            const int r = sl >> 3, c = sl & 7;
            const int lg = l0 - 8 + r;
            u16x8 v = {};
            if (lg >= 0 && lg < L_)
                v = *(const u16x8*)(qkvb + base + (size_t)(1 + lg) * QKV_COLS + 2 * E_ + hoff + c * 8);
            *(u16x8*)(kv + r * 64 + ((c ^ (r & 7)) * 8)) = v;
        }
    }
    __syncthreads();

    const size_t orow = (size_t)(b * S_ + 1 + l) * E_ + hoff;
    #pragma unroll
    for (int c = 0; c < 8; ++c) {
        float acc[8];
        #pragma unroll
        for (int i = 0; i < 8; ++i) acc[i] = s[0] * vc[c * 8 + i];
        #pragma unroll
        for (int w = 0; w < 9; ++w) {
            const int vr = t + 2 * w;
            const u16x8 vv = *(const u16x8*)(kv + vr * 64 + ((c ^ (vr & 7)) * 8));
            #pragma unroll
            for (int i = 0; i < 8; ++i) acc[i] += s[1 + w] * bf2f(vv[i]);
        }
        u16x8 o;
        #pragma unroll
        for (int i = 0; i < 8; ++i) o[i] = f2bf(acc[i] * rsum);
        *(u16x8*)(attnb + orow + c * 8) = o;
    }
}

// ---------------------------------------------------------------------------
// CLS stage 2: combine 64 chunks per (b,h). 16 blocks x 64 threads.
// ---------------------------------------------------------------------------
__global__ __launch_bounds__(64) void cls_attn_stage2(
    const float* __restrict__ part, u16* __restrict__ attnb)
{
    const int bh = blockIdx.x;
    const int lane = threadIdx.x;
    const int b = bh >> 3, h = bh & 7;
    float gm = -1e30f;
    for (int c = 0; c < NCHUNK; ++c)
        gm = fmaxf(gm, part[((size_t)bh * NCHUNK + c) * 66]);
    float gl = 0.f, ga = 0.f;
    for (int c = 0; c < NCHUNK; ++c) {
        const float* pp = part + ((size_t)bh * NCHUNK + c) * 66;
        const float w = __expf(pp[0] - gm);
        gl += pp[1] * w;
        ga += pp[2 + lane] * w;
    }
    attnb[(size_t)(b * S_) * E_ + h * D_ + lane] = f2bf(ga / gl);
}

// ---------------------------------------------------------------------------
// Launch
// ---------------------------------------------------------------------------
extern "C" void kernel_launch(void* const* d_in, const int* in_sizes, int n_in,
                              void* d_out, int out_size, void* d_ws, size_t ws_size,
                              hipStream_t stream)
{
    const float* x      = (const float*)d_in[0];
    const int*   coords = (const int*)  d_in[1];
    const float* w_qkv  = (const float*)d_in[2];
    const float* b_qkv  = (const float*)d_in[3];
    const float* w_out  = (const float*)d_in[4];
    const float* b_out  = (const float*)d_in[5];
    float* out = (float*)d_out;

    // workspace layout
    u16*   qkvb  = (u16*)d_ws;                                // M_ROWS x 1536 bf16
    u16*   attnb = qkvb + (size_t)M_ROWS * QKV_COLS;          // M_PAD x 512 bf16
    u16*   wqb   = attnb + (size_t)M_PAD * E_;                // 1536 x 512
    u16*   wob   = wqb + (size_t)QKV_COLS * E_;               // 512 x 512
    float* part  = (float*)(wob + (size_t)E_ * E_);           // 16*64*66 floats
    float2* tab  = (float2*)(part + (size_t)16 * NCHUNK * 66);// B*L*32 float2 (4 MB)

    // 1. fused prep: weight converts + rope table + attnb pad zero
    prep_kernel<<<(PREP_TOTAL + 255) / 256, 256, 0, stream>>>(
        w_qkv, w_out, coords, wqb, wob, tab, attnb);

    // 2. QKV projection (A from fp32 x directly) + fused RoPE, bf16 out
    {
        dim3 grid(QKV_COLS / 128, M_PAD / 128);   // 12 x 129
        gemm_qkv_fused<<<grid, 256, 0, stream>>>(
            x, wqb, b_qkv, qkvb, tab, M_ROWS, QKV_COLS, E_);
    }

    // 3. merged CLS stage1 + patch attention
    attn_fused<<<CLS_BLOCKS + PATCH_BLOCKS, 256, 0, stream>>>(qkvb, part, attnb);

    // 4. CLS stage 2
    cls_attn_stage2<<<B_ * H_, 64, 0, stream>>>(part, attnb);

    // 5. Output projection (fp32 out)
    {
        dim3 grid(E_ / 128, M_PAD / 128);
        gemm_out_128<<<grid, 256, 0, stream>>>(
            attnb, wob, b_out, out, M_ROWS, E_, E_);
    }
}

// Round 15
// 154.371 us; speedup vs baseline: 1.2502x; 1.0003x over previous
//
#include <hip/hip_runtime.h>
#include <math.h>

// Problem constants
#define B_ 2
#define S_ 8193
#define L_ 8192
#define E_ 512
#define H_ 8
#define D_ 64
#define QKV_COLS 1536   // 3*E
#define SCALE 0.125f
#define M_ROWS 16386    // B*S
#define M_PAD 16512     // round up to 128

typedef unsigned short u16;
typedef __attribute__((ext_vector_type(8))) short bf16x8;
typedef __attribute__((ext_vector_type(8))) unsigned short u16x8;
typedef __attribute__((ext_vector_type(4))) float f32x4;

__device__ __forceinline__ u16 f2bf(float f) {
    unsigned u = __float_as_uint(f);
    unsigned r = (u + 0x7fffu + ((u >> 16) & 1u)) >> 16;   // RNE
    return (u16)r;
}
__device__ __forceinline__ float bf2f(u16 h) {
    return __uint_as_float((unsigned)h << 16);
}

__device__ __forceinline__ void gload_lds16(const void* g, void* l) {
    __builtin_amdgcn_global_load_lds(
        (const __attribute__((address_space(1))) void*)g,
        (__attribute__((address_space(3))) void*)l, 16, 0, 0);
}

#define WAITV8() asm volatile("s_waitcnt vmcnt(8)" ::: "memory")
#define WAITV4() asm volatile("s_waitcnt vmcnt(4)" ::: "memory")
#define WAITV0() asm volatile("s_waitcnt vmcnt(0)" ::: "memory")
#define LGKM0()  asm volatile("s_waitcnt lgkmcnt(0)" ::: "memory")
#define BAR()    __builtin_amdgcn_s_barrier()

// ---------------------------------------------------------------------------
// Fused prep: wqb convert | wob convert | rope table | attnb pad zero.
// One grid-stride-free flat launch covering all four ranges.
// ---------------------------------------------------------------------------
#define PREP_W1 (QKV_COLS * E_ / 4)            // 196608 w_qkv quads
#define PREP_W2 (E_ * E_ / 4)                  // 65536 w_out quads
#define PREP_W3 (B_ * L_ * 32)                 // 524288 rope entries
#define PREP_W4 ((M_PAD - M_ROWS) * E_ / 8)    // 8064 pad chunks
#define PREP_TOTAL (PREP_W1 + PREP_W2 + PREP_W3 + PREP_W4)

__global__ __launch_bounds__(256) void prep_kernel(
    const float* __restrict__ w_qkv, const float* __restrict__ w_out,
    const int* __restrict__ coords,
    u16* __restrict__ wqb, u16* __restrict__ wob,
    float2* __restrict__ tab, u16* __restrict__ attnb)
{
    long i = (long)blockIdx.x * 256 + threadIdx.x;
    if (i < PREP_W1) {
        const float4 v = *(const float4*)(w_qkv + i * 4);
        ushort4 o = { f2bf(v.x), f2bf(v.y), f2bf(v.z), f2bf(v.w) };
        *(ushort4*)(wqb + i * 4) = o;
        return;
    }
    i -= PREP_W1;
    if (i < PREP_W2) {
        const float4 v = *(const float4*)(w_out + i * 4);
        ushort4 o = { f2bf(v.x), f2bf(v.y), f2bf(v.z), f2bf(v.w) };
        *(ushort4*)(wob + i * 4) = o;
        return;
    }
    i -= PREP_W2;
    if (i < PREP_W3) {
        const int p2 = (int)i & 31;
        const int bl = (int)i >> 5;
        const float coord = (float)coords[(size_t)bl * 2 + (p2 >> 4)] * 1e-5f;
        const float inv = exp2f(-0.83048202372184f * (float)(p2 & 15));
        float sn, cs;
        __sincosf(coord * inv, &sn, &cs);
        tab[i] = make_float2(cs, sn);
        return;
    }
    i -= PREP_W3;
    if (i < PREP_W4) {
        u16x8 z = {};
        *(u16x8*)(attnb + (size_t)M_ROWS * E_ + i * 8) = z;
    }
}

// ---------------------------------------------------------------------------
// QKV GEMM with fused fp32->bf16 A-staging (reg-staged) + fused RoPE.
// C = bf16( RoPE( X @ W^T + bias ) ).  X fp32 M x K, W bf16 N x K.
// 128x128 tile, BK=32, 4 waves. Depth-2 rings, one barrier per step.
// (R12 best variant, verbatim.)
// ---------------------------------------------------------------------------
__global__ __launch_bounds__(256) void gemm_qkv_fused(
    const float* __restrict__ X, const u16* __restrict__ W,
    const float* __restrict__ bias, u16* __restrict__ C,
    const float2* __restrict__ tab, int M, int N, int K)
{
    __shared__ __align__(16) u16 smem[16384];   // As0 As1 Bs0 Bs1 (8 KB each)

    const int nwg = gridDim.x * gridDim.y;
    const int orig = blockIdx.y * gridDim.x + blockIdx.x;
    const int qq = nwg >> 3, rr = nwg & 7;
    const int xcd = orig & 7, off = orig >> 3;
    const int wgid = (xcd < rr ? xcd * (qq + 1) : rr * (qq + 1) + (xcd - rr) * qq) + off;
    const int m0 = (wgid / gridDim.x) * 128;
    const int n0 = (wgid % gridDim.x) * 128;

    const int tid  = threadIdx.x;
    const int wid  = tid >> 6;
    const int lane = tid & 63;
    const int wm = (wid >> 1) * 64;
    const int wn = (wid & 1) * 64;
    const int fr = lane & 15;
    const int fq = lane >> 4;
    const int sfq = (fq ^ ((fr >> 1) & 3)) * 8;

    const int r0 = tid >> 3;
    const int c4 = tid & 7;
    const int aoff = r0 * 32 + (((c4 >> 1) ^ ((r0 >> 1) & 3)) * 8) + (c4 & 1) * 4;

    const int srow = lane >> 2;
    const int scol = ((lane & 3) ^ ((lane >> 3) & 3)) * 8;
    const int c0 = wid * 2, c1 = wid * 2 + 1;
    const u16* gb0 = W + (size_t)(n0 + c0 * 16 + srow) * K + scol;
    const u16* gb1 = W + (size_t)(n0 + c1 * 16 + srow) * K + scol;
    const int lb0 = c0 * 16 * 32, lb1 = c1 * 16 * 32;

    float4 ra[4];
    f32x4 acc[4][4] = {};

    #define ALOAD(k0)                                                           \
        do {                                                                    \
            _Pragma("unroll")                                                   \
            for (int i = 0; i < 4; ++i) {                                       \
                const int gm = m0 + r0 + 32 * i;                                \
                ra[i] = (gm < M)                                                \
                    ? *(const float4*)(X + (size_t)gm * K + (k0) + c4 * 4)      \
                    : make_float4(0.f, 0.f, 0.f, 0.f);                          \
            }                                                                   \
        } while (0)

    #define ADSW(buf)                                                           \
        do {                                                                    \
            u16* as_ = smem + (buf) * 4096;                                     \
            _Pragma("unroll")                                                   \
            for (int i = 0; i < 4; ++i) {                                       \
                ushort4 o;                                                      \
                o.x = f2bf(ra[i].x); o.y = f2bf(ra[i].y);                       \
                o.z = f2bf(ra[i].z); o.w = f2bf(ra[i].w);                       \
                *(ushort4*)(as_ + aoff + 1024 * i) = o;                         \
            }                                                                   \
        } while (0)

    #define WSTAGE(buf, k0)                                                     \
        do {                                                                    \
            u16* bs_ = smem + 8192 + (buf) * 4096;                              \
            gload_lds16(gb0 + (k0), bs_ + lb0);                                 \
            gload_lds16(gb1 + (k0), bs_ + lb1);                                 \
        } while (0)

    #define COMPUTE(buf)                                                         \
        do {                                                                     \
            const u16* as_ = smem + (buf) * 4096;                                \
            const u16* bs_ = smem + 8192 + (buf) * 4096;                         \
            bf16x8 a[4], b[4];                                                   \
            _Pragma("unroll")                                                    \
            for (int mi = 0; mi < 4; ++mi)                                       \
                a[mi] = *(const bf16x8*)(as_ + (wm + mi * 16 + fr) * 32 + sfq);  \
            _Pragma("unroll")                                                    \
            for (int ni = 0; ni < 4; ++ni)                                       \
                b[ni] = *(const bf16x8*)(bs_ + (wn + ni * 16 + fr) * 32 + sfq);  \
            _Pragma("unroll")                                                    \
            for (int mi = 0; mi < 4; ++mi)                                       \
                _Pragma("unroll")                                                \
                for (int ni = 0; ni < 4; ++ni)                                   \
                    acc[mi][ni] = __builtin_amdgcn_mfma_f32_16x16x32_bf16(       \
                        a[mi], b[ni], acc[mi][ni], 0, 0, 0);                     \
        } while (0)

    const int nt = K / 32;   // 16

    ALOAD(0); WSTAGE(0, 0);
    WAITV0();
    ADSW(0);
    ALOAD(32); WSTAGE(1, 32);
    LGKM0(); BAR();

    for (int t = 0; t < nt; ++t) {
        COMPUTE(t & 1);
        if (t + 1 < nt) {
            WAITV0();
            ADSW((t + 1) & 1);
            if (t + 2 < nt) ALOAD((t + 2) * 32);
            LGKM0(); BAR();
            if (t + 2 < nt) WSTAGE(t & 1, (t + 2) * 32);
        }
    }

    #undef ALOAD
    #undef ADSW
    #undef WSTAGE
    #undef COMPUTE

    __syncthreads();

    u16* st = smem;                           // 128 x 128 bf16 = 32 KB
    const bool rope_blk = (n0 < 2 * E_);
    #pragma unroll
    for (int mi = 0; mi < 4; ++mi) {
        #pragma unroll
        for (int j = 0; j < 4; ++j) {
            const int row = wm + mi * 16 + fq * 4 + j;
            const int gm = m0 + row;
            int b = 0, s = gm;
            if (gm >= S_) { b = 1; s = gm - S_; }
            const bool rot = rope_blk && (gm < M) && (s > 0);
            const float2* trow = tab + ((size_t)(b * L_ + (s - 1)) << 5);
            #pragma unroll
            for (int ni = 0; ni < 4; ++ni) {
                const int col = wn + ni * 16 + fr;
                const int gn = n0 + col;
                float v = acc[mi][ni][j] + bias[gn];
                const float partner = __shfl_xor(v, 1, 64);
                if (rot) {
                    const float2 tt = trow[(gn & 63) >> 1];
                    v = (gn & 1) ? (v * tt.x + partner * tt.y)
                                 : (v * tt.x - partner * tt.y);
                }
                st[row * 128 + col] = f2bf(v);
            }
        }
    }
    __syncthreads();
    #pragma unroll
    for (int i = 0; i < 8; ++i) {
        const int ch = i * 256 + tid;
        const int row = ch >> 4;
        const int coff = (ch & 15) * 8;
        const int gm = m0 + row;
        if (gm < M)
            *(u16x8*)(C + (size_t)gm * N + n0 + coff) =
                *(const u16x8*)(st + row * 128 + coff);
    }
}

// ---------------------------------------------------------------------------
// Out-proj GEMM (fp32 out), 128x128 tile, depth-3 counted-vmcnt pipeline,
// LDS-staged coalesced C-write. (R12, unchanged.)
// ---------------------------------------------------------------------------
__global__ __launch_bounds__(256) void gemm_out_128(
    const u16* __restrict__ A, const u16* __restrict__ W,
    const float* __restrict__ bias, float* __restrict__ C,
    int M, int N, int K)
{
    __shared__ __align__(16) u16 smem[32768];

    const int nwg = gridDim.x * gridDim.y;
    const int orig = blockIdx.y * gridDim.x + blockIdx.x;
    const int qq = nwg >> 3, rr = nwg & 7;
    const int xcd = orig & 7, off = orig >> 3;
    const int wgid = (xcd < rr ? xcd * (qq + 1) : rr * (qq + 1) + (xcd - rr) * qq) + off;
    const int m0 = (wgid / gridDim.x) * 128;
    const int n0 = (wgid % gridDim.x) * 128;

    const int tid  = threadIdx.x;
    const int wid  = tid >> 6;
    const int lane = tid & 63;
    const int wm = (wid >> 1) * 64;
    const int wn = (wid & 1) * 64;

    const int srow = lane >> 2;
    const int scol = ((lane & 3) ^ ((lane >> 3) & 3)) * 8;
    const int fr = lane & 15;
    const int fq = lane >> 4;
    const int sfq = (fq ^ ((fr >> 1) & 3)) * 8;

    const int c0 = wid * 2, c1 = wid * 2 + 1;
    const u16* ga0 = A + (size_t)(m0 + c0 * 16 + srow) * K + scol;
    const u16* ga1 = A + (size_t)(m0 + c1 * 16 + srow) * K + scol;
    const u16* gb0 = W + (size_t)(n0 + c0 * 16 + srow) * K + scol;
    const u16* gb1 = W + (size_t)(n0 + c1 * 16 + srow) * K + scol;
    const int la0 = c0 * 16 * 32, la1 = c1 * 16 * 32;

    f32x4 acc[4][4] = {};

    #define STAGE(bi, k0)                                       \
        do {                                                    \
            u16* as_ = smem + (bi) * 4096;                      \
            u16* bs_ = smem + 16384 + (bi) * 4096;              \
            gload_lds16(ga0 + (k0), as_ + la0);                 \
            gload_lds16(ga1 + (k0), as_ + la1);                 \
            gload_lds16(gb0 + (k0), bs_ + la0);                 \
            gload_lds16(gb1 + (k0), bs_ + la1);                 \
        } while (0)

    #define COMPUTE(bi)                                                          \
        do {                                                                     \
            const u16* as_ = smem + (bi) * 4096;                                 \
            const u16* bs_ = smem + 16384 + (bi) * 4096;                         \
            bf16x8 a[4], b[4];                                                   \
            _Pragma("unroll")                                                    \
            for (int mi = 0; mi < 4; ++mi)                                       \
                a[mi] = *(const bf16x8*)(as_ + (wm + mi * 16 + fr) * 32 + sfq);  \
            _Pragma("unroll")                                                    \
            for (int ni = 0; ni < 4; ++ni)                                       \
                b[ni] = *(const bf16x8*)(bs_ + (wn + ni * 16 + fr) * 32 + sfq);  \
            _Pragma("unroll")                                                    \
            for (int mi = 0; mi < 4; ++mi)                                       \
                _Pragma("unroll")                                                \
                for (int ni = 0; ni < 4; ++ni)                                   \
                    acc[mi][ni] = __builtin_amdgcn_mfma_f32_16x16x32_bf16(       \
                        a[mi], b[ni], acc[mi][ni], 0, 0, 0);                     \
        } while (0)

    const int nt = K / 32;

    STAGE(0, 0);
    STAGE(1, 32);
    STAGE(2, 64);

    int t = 0;
    for (; t <= nt - 4; ++t) {
        WAITV8(); BAR();
        COMPUTE(t & 3);
        STAGE((t + 3) & 3, (t + 3) * 32);
    }
    WAITV8(); BAR(); COMPUTE(t & 3); ++t;
    WAITV4(); BAR(); COMPUTE(t & 3); ++t;
    WAITV0(); BAR(); COMPUTE(t & 3);

    #undef STAGE
    #undef COMPUTE

    __syncthreads();

    float* stf = (float*)smem;
    #pragma unroll
    for (int mi = 0; mi < 4; ++mi)
        #pragma unroll
        for (int j = 0; j < 4; ++j) {
            const int r = wm + mi * 16 + fq * 4 + j;
            #pragma unroll
            for (int ni = 0; ni < 4; ++ni) {
                const int c = wn + ni * 16 + fr;
                stf[r * 128 + c] = acc[mi][ni][j] + bias[n0 + c];
            }
        }
    __syncthreads();
    #pragma unroll
    for (int i = 0; i < 16; ++i) {
        const int ch = i * 256 + tid;
        const int row = ch >> 5;
        const int coff = (ch & 31) * 4;
        const int gm = m0 + row;
        if (gm < M)
            *(float4*)(C + (size_t)gm * N + n0 + coff) =
                *(const float4*)(stf + row * 128 + coff);
    }
}

// ---------------------------------------------------------------------------
// Merged attention: blocks [0, 1024) = cls stage 1; [1024, 1536) = patch.
// Both read qkvb; outputs disjoint. 256 threads.
// Patch: 256 queries/block, 272-row K/V window staged in swizzled LDS.
// ---------------------------------------------------------------------------
#define NCHUNK 64
#define CLS_ROWS 129             // ceil(8193/64)
#define CLS_BLOCKS (B_ * H_ * NCHUNK)   // 1024
#define PQT 256
#define PATCH_BLOCKS (B_ * H_ * (L_ / PQT))  // 512

__global__ __launch_bounds__(256) void attn_fused(
    const u16* __restrict__ qkvb, float* __restrict__ part,
    u16* __restrict__ attnb)
{
    __shared__ __align__(16) u16 sbuf[272 * 64];   // patch K/V window (34.8 KB)
    __shared__ float kcvc[128];
    __shared__ float sm4[4], sl4[4];

    const int blk = blockIdx.x;

    if (blk < CLS_BLOCKS) {
        // ---------------- CLS stage 1 ----------------
        const int bh = blk >> 6, ch = blk & 63;
        const int b = bh >> 3, h = bh & 7;
        const int wid = threadIdx.x >> 6, lane = threadIdx.x & 63;
        const size_t base = (size_t)b * S_ * QKV_COLS;

        const float q = bf2f(qkvb[base + h * D_ + lane]);

        const int lo = ch * CLS_ROWS;
        const int hi = (lo + CLS_ROWS < S_) ? lo + CLS_ROWS : S_;

        float m = -1e30f, lsum = 0.f, acc = 0.f;
        for (int j = lo + wid; j < hi; j += 4) {
            const size_t roff = base + (size_t)j * QKV_COLS;
            float t = q * bf2f(qkvb[roff + E_ + h * D_ + lane]);
            #pragma unroll
            for (int o = 32; o; o >>= 1) t += __shfl_xor(t, o, 64);
            t *= SCALE;
            const float mn = fmaxf(m, t);
            const float corr = __expf(m - mn);
            const float p = __expf(t - mn);
            lsum = lsum * corr + p;
            acc = acc * corr + p * bf2f(qkvb[roff + 2 * E_ + h * D_ + lane]);
            m = mn;
        }

        float* sacc = (float*)sbuf;   // 4 x 64 floats
        if (lane == 0) { sm4[wid] = m; sl4[wid] = lsum; }
        sacc[wid * 64 + lane] = acc;
        __syncthreads();
        if (wid == 0) {
            const float gm = fmaxf(fmaxf(sm4[0], sm4[1]), fmaxf(sm4[2], sm4[3]));
            float gl = 0.f, ga = 0.f;
            #pragma unroll
            for (int w = 0; w < 4; ++w) {
                const float c = __expf(sm4[w] - gm);
                gl += sl4[w] * c;
                ga += sacc[w * 64 + lane] * c;
            }
            float* pp = part + ((size_t)bh * NCHUNK + ch) * 66;
            if (lane == 0) { pp[0] = gm; pp[1] = gl; }
            pp[2 + lane] = ga;
        }
        return;
    }

    // ---------------- patch attention ----------------
    const int pblk = blk - CLS_BLOCKS;
    const int qt = pblk & 31;              // 32 tiles
    const int h = (pblk >> 5) & 7;
    const int b = pblk >> 8;
    const int l0 = qt * PQT;
    const size_t base = (size_t)b * S_ * QKV_COLS;
    const int hoff = h * D_;

    u16* kv = sbuf;
    float* kc = kcvc;
    float* vc = kcvc + 64;

    const int t = threadIdx.x;

    if (t < 64) kc[t] = bf2f(qkvb[base + E_ + hoff + t]);
    else if (t < 128) vc[t - 64] = bf2f(qkvb[base + 2 * E_ + hoff + (t - 64)]);

    // stage K rows l0-8 .. l0+263 (272 rows x 8 chunks = 2176 slots)
    #pragma unroll
    for (int i = 0; i < 9; ++i) {
        const int s = i * 256 + t;
        if (s < 272 * 8) {
            const int r = s >> 3, c = s & 7;
            const int lg = l0 - 8 + r;
            u16x8 v = {};
            if (lg >= 0 && lg < L_)
                v = *(const u16x8*)(qkvb + base + (size_t)(1 + lg) * QKV_COLS + E_ + hoff + c * 8);
            *(u16x8*)(kv + r * 64 + ((c ^ (r & 7)) * 8)) = v;
        }
    }
    __syncthreads();

    const int l = l0 + t;
    const size_t qrow = base + (size_t)(1 + l) * QKV_COLS + hoff;

    float s[10];
    #pragma unroll
    for (int w = 0; w < 10; ++w) s[w] = 0.f;

    #pragma unroll
    for (int c = 0; c < 8; ++c) {
        const u16x8 qv = *(const u16x8*)(qkvb + qrow + c * 8);
        float qf[8];
        #pragma unroll
        for (int i = 0; i < 8; ++i) qf[i] = bf2f(qv[i]);
        #pragma unroll
        for (int i = 0; i < 8; ++i) s[0] += qf[i] * kc[c * 8 + i];
        #pragma unroll
        for (int w = 0; w < 9; ++w) {
            const int kr = t + 2 * w;
            const u16x8 kk = *(const u16x8*)(kv + kr * 64 + ((c ^ (kr & 7)) * 8));
            #pragma unroll
            for (int i = 0; i < 8; ++i) s[1 + w] += qf[i] * bf2f(kk[i]);
        }
    }

    s[0] *= SCALE;
    #pragma unroll
    for (int w = 0; w < 9; ++w) {
        const int lp = l + 2 * w - 8;
        s[1 + w] = (lp >= 0 && lp < L_) ? s[1 + w] * SCALE : -1e30f;
    }
    float m = s[0];
    #pragma unroll
    for (int w = 1; w < 10; ++w) m = fmaxf(m, s[w]);
    float sum = 0.f;
    #pragma unroll
    for (int w = 0; w < 10; ++w) { s[w] = __expf(s[w] - m); sum += s[w]; }
    const float rsum = 1.0f / sum;

    // restage V over K
    __syncthreads();
    #pragma unroll
    for (int i = 0; i < 9; ++i) {
        const int sl = i * 256 + t;
        if (sl < 272 * 8) {
            const int r = sl >> 3, c = sl & 7;
            const int lg = l0 - 8 + r;
            u16x8 v = {};
            if (lg >= 0 && lg < L_)
                v = *(const u16x8*)(qkvb + base + (size_t)(1 + lg) * QKV_COLS + 2 * E_ + hoff + c * 8);
            *(u16x8*)(kv + r * 64 + ((c ^ (r & 7)) * 8)) = v;
        }
    }
    __syncthreads();

    const size_t orow = (size_t)(b * S_ + 1 + l) * E_ + hoff;
    #pragma unroll
    for (int c = 0; c < 8; ++c) {
        float acc[8];
        #pragma unroll
        for (int i = 0; i < 8; ++i) acc[i] = s[0] * vc[c * 8 + i];
        #pragma unroll
        for (int w = 0; w < 9; ++w) {
            const int vr = t + 2 * w;
            const u16x8 vv = *(const u16x8*)(kv + vr * 64 + ((c ^ (vr & 7)) * 8));
            #pragma unroll
            for (int i = 0; i < 8; ++i) acc[i] += s[1 + w] * bf2f(vv[i]);
        }
        u16x8 o;
        #pragma unroll
        for (int i = 0; i < 8; ++i) o[i] = f2bf(acc[i] * rsum);
        *(u16x8*)(attnb + orow + c * 8) = o;
    }
}

// ---------------------------------------------------------------------------
// CLS stage 2: combine 64 chunks per (b,h). 16 blocks x 64 threads.
// ---------------------------------------------------------------------------
__global__ __launch_bounds__(64) void cls_attn_stage2(
    const float* __restrict__ part, u16* __restrict__ attnb)
{
    const int bh = blockIdx.x;
    const int lane = threadIdx.x;
    const int b = bh >> 3, h = bh & 7;
    float gm = -1e30f;
    for (int c = 0; c < NCHUNK; ++c)
        gm = fmaxf(gm, part[((size_t)bh * NCHUNK + c) * 66]);
    float gl = 0.f, ga = 0.f;
    for (int c = 0; c < NCHUNK; ++c) {
        const float* pp = part + ((size_t)bh * NCHUNK + c) * 66;
        const float w = __expf(pp[0] - gm);
        gl += pp[1] * w;
        ga += pp[2 + lane] * w;
    }
    attnb[(size_t)(b * S_) * E_ + h * D_ + lane] = f2bf(ga / gl);
}

// ---------------------------------------------------------------------------
// Launch
// ---------------------------------------------------------------------------
extern "C" void kernel_launch(void* const* d_in, const int* in_sizes, int n_in,
                              void* d_out, int out_size, void* d_ws, size_t ws_size,
                              hipStream_t stream)
{
    const float* x      = (const float*)d_in[0];
    const int*   coords = (const int*)  d_in[1];
    const float* w_qkv  = (const float*)d_in[2];
    const float* b_qkv  = (const float*)d_in[3];
    const float* w_out  = (const float*)d_in[4];
    const float* b_out  = (const float*)d_in[5];
    float* out = (float*)d_out;

    // workspace layout
    u16*   qkvb  = (u16*)d_ws;                                // M_ROWS x 1536 bf16
    u16*   attnb = qkvb + (size_t)M_ROWS * QKV_COLS;          // M_PAD x 512 bf16
    u16*   wqb   = attnb + (size_t)M_PAD * E_;                // 1536 x 512
    u16*   wob   = wqb + (size_t)QKV_COLS * E_;               // 512 x 512
    float* part  = (float*)(wob + (size_t)E_ * E_);           // 16*64*66 floats
    float2* tab  = (float2*)(part + (size_t)16 * NCHUNK * 66);// B*L*32 float2 (4 MB)

    // 1. fused prep: weight converts + rope table + attnb pad zero
    prep_kernel<<<(PREP_TOTAL + 255) / 256, 256, 0, stream>>>(
        w_qkv, w_out, coords, wqb, wob, tab, attnb);

    // 2. QKV projection (A from fp32 x directly) + fused RoPE, bf16 out
    {
        dim3 grid(QKV_COLS / 128, M_PAD / 128);   // 12 x 129
        gemm_qkv_fused<<<grid, 256, 0, stream>>>(
            x, wqb, b_qkv, qkvb, tab, M_ROWS, QKV_COLS, E_);
    }

    // 3. merged CLS stage1 + patch attention
    attn_fused<<<CLS_BLOCKS + PATCH_BLOCKS, 256, 0, stream>>>(qkvb, part, attnb);

    // 4. CLS stage 2
    cls_attn_stage2<<<B_ * H_, 64, 0, stream>>>(part, attnb);

    // 5. Output projection (fp32 out)
    {
        dim3 grid(E_ / 128, M_PAD / 128);
        gemm_out_128<<<grid, 256, 0, stream>>>(
            attnb, wob, b_out, out, M_ROWS, E_, E_);
    }
}

// Round 16
// 142.951 us; speedup vs baseline: 1.3501x; 1.0799x over previous
//
#include <hip/hip_runtime.h>
#include <math.h>

// Problem constants
#define B_ 2
#define S_ 8193
#define L_ 8192
#define E_ 512
#define H_ 8
#define D_ 64
#define QKV_COLS 1536   // 3*E
#define SCALE 0.125f
#define M_ROWS 16386    // B*S
#define M_PAD 16512     // round up to 128

typedef unsigned short u16;
typedef __attribute__((ext_vector_type(8))) short bf16x8;
typedef __attribute__((ext_vector_type(8))) unsigned short u16x8;
typedef __attribute__((ext_vector_type(4))) float f32x4;

__device__ __forceinline__ u16 f2bf(float f) {
    unsigned u = __float_as_uint(f);
    unsigned r = (u + 0x7fffu + ((u >> 16) & 1u)) >> 16;   // RNE
    return (u16)r;
}
__device__ __forceinline__ float bf2f(u16 h) {
    return __uint_as_float((unsigned)h << 16);
}

__device__ __forceinline__ void gload_lds16(const void* g, void* l) {
    __builtin_amdgcn_global_load_lds(
        (const __attribute__((address_space(1))) void*)g,
        (__attribute__((address_space(3))) void*)l, 16, 0, 0);
}

#define WAITV8() asm volatile("s_waitcnt vmcnt(8)" ::: "memory")
#define WAITV4() asm volatile("s_waitcnt vmcnt(4)" ::: "memory")
#define WAITV0() asm volatile("s_waitcnt vmcnt(0)" ::: "memory")
#define LGKM0()  asm volatile("s_waitcnt lgkmcnt(0)" ::: "memory")
#define BAR()    __builtin_amdgcn_s_barrier()

// ---------------------------------------------------------------------------
// Fused prep: wqb convert | wob convert | rope table | attnb pad zero.
// ---------------------------------------------------------------------------
#define PREP_W1 (QKV_COLS * E_ / 4)            // 196608 w_qkv quads
#define PREP_W2 (E_ * E_ / 4)                  // 65536 w_out quads
#define PREP_W3 (B_ * L_ * 32)                 // 524288 rope entries
#define PREP_W4 ((M_PAD - M_ROWS) * E_ / 8)    // 8064 pad chunks
#define PREP_TOTAL (PREP_W1 + PREP_W2 + PREP_W3 + PREP_W4)

__global__ __launch_bounds__(256) void prep_kernel(
    const float* __restrict__ w_qkv, const float* __restrict__ w_out,
    const int* __restrict__ coords,
    u16* __restrict__ wqb, u16* __restrict__ wob,
    float2* __restrict__ tab, u16* __restrict__ attnb)
{
    long i = (long)blockIdx.x * 256 + threadIdx.x;
    if (i < PREP_W1) {
        const float4 v = *(const float4*)(w_qkv + i * 4);
        ushort4 o = { f2bf(v.x), f2bf(v.y), f2bf(v.z), f2bf(v.w) };
        *(ushort4*)(wqb + i * 4) = o;
        return;
    }
    i -= PREP_W1;
    if (i < PREP_W2) {
        const float4 v = *(const float4*)(w_out + i * 4);
        ushort4 o = { f2bf(v.x), f2bf(v.y), f2bf(v.z), f2bf(v.w) };
        *(ushort4*)(wob + i * 4) = o;
        return;
    }
    i -= PREP_W2;
    if (i < PREP_W3) {
        const int p2 = (int)i & 31;
        const int bl = (int)i >> 5;
        const float coord = (float)coords[(size_t)bl * 2 + (p2 >> 4)] * 1e-5f;
        const float inv = exp2f(-0.83048202372184f * (float)(p2 & 15));
        float sn, cs;
        __sincosf(coord * inv, &sn, &cs);
        tab[i] = make_float2(cs, sn);
        return;
    }
    i -= PREP_W3;
    if (i < PREP_W4) {
        u16x8 z = {};
        *(u16x8*)(attnb + (size_t)M_ROWS * E_ + i * 8) = z;
    }
}

// ---------------------------------------------------------------------------
// QKV GEMM, 8-wave TLP variant: 128x128 tile, BK=32, 512 threads (2M x 4N
// waves, wave output 64x32, acc 4x2 frags = 32 VGPR). Reg-staged fp32 A ->
// bf16 ds_write (swizzled); W one gload_lds16 per thread. Depth-2 rings,
// one barrier per step (R12-proven loop). Fused RoPE epilogue + LDS-staged
// coalesced bf16 C-write. LDS 32 KB -> up to 3 blocks/CU (24 waves).
// Swizzle: LDS chunk slot s of row r holds global 16B-chunk s^(r&3).
// ---------------------------------------------------------------------------
__global__ __launch_bounds__(512, 4) void gemm_qkv_fused(
    const float* __restrict__ X, const u16* __restrict__ W,
    const float* __restrict__ bias, u16* __restrict__ C,
    const float2* __restrict__ tab, int M, int N, int K)
{
    __shared__ __align__(16) u16 smem[16384];   // A0 A1 @0/4096, B0 B1 @8192/12288

    // XCD-aware bijective swizzle (m204)
    const int nwg = gridDim.x * gridDim.y;
    const int orig = blockIdx.y * gridDim.x + blockIdx.x;
    const int qq = nwg >> 3, rr = nwg & 7;
    const int xcd = orig & 7, off = orig >> 3;
    const int wgid = (xcd < rr ? xcd * (qq + 1) : rr * (qq + 1) + (xcd - rr) * qq) + off;
    const int m0 = (wgid / gridDim.x) * 128;
    const int n0 = (wgid % gridDim.x) * 128;

    const int tid  = threadIdx.x;
    const int wid  = tid >> 6;
    const int lane = tid & 63;
    const int wm = (wid >> 2) * 64;    // 2 M-waves
    const int wn = (wid & 3) * 32;     // 4 N-waves
    const int fr = lane & 15;
    const int fq = lane >> 4;          // 0..3

    // A loader: rows r0, r0+64; cols c8*4..+3 (f32)
    const int r0 = tid >> 3;
    const int c8 = tid & 7;
    const int aoff0 = r0 * 32 + (((c8 >> 1) ^ (r0 & 3)) * 8) + (c8 & 1) * 4;  // u16 units

    // W loader: one 16B chunk per thread; slot tid -> row=tid>>2, ch=tid&3
    const int wrow = tid >> 2;
    const int wch  = (tid & 3) ^ (wrow & 3);   // swizzled source chunk

    float4 ra[2];
    f32x4 acc[4][2] = {};

    #define ALOAD(k0)                                                           \
        do {                                                                    \
            _Pragma("unroll")                                                   \
            for (int i = 0; i < 2; ++i) {                                       \
                const int gm = m0 + r0 + 64 * i;                                \
                ra[i] = (gm < M)                                                \
                    ? *(const float4*)(X + (size_t)gm * K + (k0) + c8 * 4)      \
                    : make_float4(0.f, 0.f, 0.f, 0.f);                          \
            }                                                                   \
        } while (0)

    #define ADSW(buf)                                                           \
        do {                                                                    \
            u16* as_ = smem + (buf) * 4096;                                     \
            _Pragma("unroll")                                                   \
            for (int i = 0; i < 2; ++i) {                                       \
                ushort4 o;                                                      \
                o.x = f2bf(ra[i].x); o.y = f2bf(ra[i].y);                       \
                o.z = f2bf(ra[i].z); o.w = f2bf(ra[i].w);                       \
                *(ushort4*)(as_ + aoff0 + 2048 * i) = o;                        \
            }                                                                   \
        } while (0)

    #define WSTAGE(buf, k0)                                                     \
        gload_lds16(W + (size_t)(n0 + wrow) * K + (k0) + wch * 8,               \
                    smem + 8192 + (buf) * 4096 + wid * 512)

    #define COMPUTE(buf)                                                         \
        do {                                                                     \
            const u16* as_ = smem + (buf) * 4096;                                \
            const u16* bs_ = smem + 8192 + (buf) * 4096;                         \
            bf16x8 a[4], b[2];                                                   \
            _Pragma("unroll")                                                    \
            for (int mi = 0; mi < 4; ++mi) {                                     \
                const int r_ = wm + mi * 16 + fr;                                \
                a[mi] = *(const bf16x8*)(as_ + r_ * 32 + ((fq ^ (r_ & 3)) * 8)); \
            }                                                                    \
            _Pragma("unroll")                                                    \
            for (int ni = 0; ni < 2; ++ni) {                                     \
                const int r_ = wn + ni * 16 + fr;                                \
                b[ni] = *(const bf16x8*)(bs_ + r_ * 32 + ((fq ^ (r_ & 3)) * 8)); \
            }                                                                    \
            _Pragma("unroll")                                                    \
            for (int mi = 0; mi < 4; ++mi)                                       \
                _Pragma("unroll")                                                \
                for (int ni = 0; ni < 2; ++ni)                                   \
                    acc[mi][ni] = __builtin_amdgcn_mfma_f32_16x16x32_bf16(       \
                        a[mi], b[ni], acc[mi][ni], 0, 0, 0);                     \
        } while (0)

    const int nt = K / 32;   // 16

    ALOAD(0); WSTAGE(0, 0);
    WAITV0();
    ADSW(0);
    ALOAD(32); WSTAGE(1, 32);
    LGKM0(); BAR();

    for (int t = 0; t < nt; ++t) {
        COMPUTE(t & 1);
        if (t + 1 < nt) {
            WAITV0();                 // A regs(t+1) + W lds(t+1) landed
            ADSW((t + 1) & 1);        // target buf last read at t-1 (BAR'd)
            if (t + 2 < nt) ALOAD((t + 2) * 32);
            LGKM0(); BAR();           // ds_writes visible; all waves done COMPUTE(t)
            if (t + 2 < nt) WSTAGE(t & 1, (t + 2) * 32);   // free after BAR
        }
    }

    #undef ALOAD
    #undef ADSW
    #undef WSTAGE
    #undef COMPUTE

    __syncthreads();   // release LDS; reuse as 128x128 bf16 C staging

    u16* st = smem;
    const bool rope_blk = (n0 < 2 * E_);
    #pragma unroll
    for (int mi = 0; mi < 4; ++mi) {
        #pragma unroll
        for (int j = 0; j < 4; ++j) {
            const int row = wm + mi * 16 + fq * 4 + j;
            const int gm = m0 + row;
            int b = 0, s = gm;
            if (gm >= S_) { b = 1; s = gm - S_; }
            const bool rot = rope_blk && (gm < M) && (s > 0);
            const float2* trow = tab + ((size_t)(b * L_ + (s - 1)) << 5);
            #pragma unroll
            for (int ni = 0; ni < 2; ++ni) {
                const int col = wn + ni * 16 + fr;
                const int gn = n0 + col;
                float v = acc[mi][ni][j] + bias[gn];
                const float partner = __shfl_xor(v, 1, 64);  // gn^1 lives in lane^1
                if (rot) {
                    const float2 tt = trow[(gn & 63) >> 1];
                    v = (gn & 1) ? (v * tt.x + partner * tt.y)
                                 : (v * tt.x - partner * tt.y);
                }
                st[row * 128 + col] = f2bf(v);
            }
        }
    }
    __syncthreads();
    #pragma unroll
    for (int i = 0; i < 4; ++i) {
        const int slot = i * 512 + tid;
        const int row = slot >> 4;
        const int coff = (slot & 15) * 8;
        const int gm = m0 + row;
        if (gm < M)
            *(u16x8*)(C + (size_t)gm * N + n0 + coff) =
                *(const u16x8*)(st + row * 128 + coff);
    }
}

// ---------------------------------------------------------------------------
// Out-proj GEMM (fp32 out), 128x128 tile, depth-3 counted-vmcnt pipeline,
// LDS-staged coalesced C-write. (unchanged)
// ---------------------------------------------------------------------------
__global__ __launch_bounds__(256) void gemm_out_128(
    const u16* __restrict__ A, const u16* __restrict__ W,
    const float* __restrict__ bias, float* __restrict__ C,
    int M, int N, int K)
{
    __shared__ __align__(16) u16 smem[32768];

    const int nwg = gridDim.x * gridDim.y;
    const int orig = blockIdx.y * gridDim.x + blockIdx.x;
    const int qq = nwg >> 3, rr = nwg & 7;
    const int xcd = orig & 7, off = orig >> 3;
    const int wgid = (xcd < rr ? xcd * (qq + 1) : rr * (qq + 1) + (xcd - rr) * qq) + off;
    const int m0 = (wgid / gridDim.x) * 128;
    const int n0 = (wgid % gridDim.x) * 128;

    const int tid  = threadIdx.x;
    const int wid  = tid >> 6;
    const int lane = tid & 63;
    const int wm = (wid >> 1) * 64;
    const int wn = (wid & 1) * 64;

    const int srow = lane >> 2;
    const int scol = ((lane & 3) ^ ((lane >> 3) & 3)) * 8;
    const int fr = lane & 15;
    const int fq = lane >> 4;
    const int sfq = (fq ^ ((fr >> 1) & 3)) * 8;

    const int c0 = wid * 2, c1 = wid * 2 + 1;
    const u16* ga0 = A + (size_t)(m0 + c0 * 16 + srow) * K + scol;
    const u16* ga1 = A + (size_t)(m0 + c1 * 16 + srow) * K + scol;
    const u16* gb0 = W + (size_t)(n0 + c0 * 16 + srow) * K + scol;
    const u16* gb1 = W + (size_t)(n0 + c1 * 16 + srow) * K + scol;
    const int la0 = c0 * 16 * 32, la1 = c1 * 16 * 32;

    f32x4 acc[4][4] = {};

    #define STAGE(bi, k0)                                       \
        do {                                                    \
            u16* as_ = smem + (bi) * 4096;                      \
            u16* bs_ = smem + 16384 + (bi) * 4096;              \
            gload_lds16(ga0 + (k0), as_ + la0);                 \
            gload_lds16(ga1 + (k0), as_ + la1);                 \
            gload_lds16(gb0 + (k0), bs_ + la0);                 \
            gload_lds16(gb1 + (k0), bs_ + la1);                 \
        } while (0)

    #define COMPUTE(bi)                                                          \
        do {                                                                     \
            const u16* as_ = smem + (bi) * 4096;                                 \
            const u16* bs_ = smem + 16384 + (bi) * 4096;                         \
            bf16x8 a[4], b[4];                                                   \
            _Pragma("unroll")                                                    \
            for (int mi = 0; mi < 4; ++mi)                                       \
                a[mi] = *(const bf16x8*)(as_ + (wm + mi * 16 + fr) * 32 + sfq);  \
            _Pragma("unroll")                                                    \
            for (int ni = 0; ni < 4; ++ni)                                       \
                b[ni] = *(const bf16x8*)(bs_ + (wn + ni * 16 + fr) * 32 + sfq);  \
            _Pragma("unroll")                                                    \
            for (int mi = 0; mi < 4; ++mi)                                       \
                _Pragma("unroll")                                                \
                for (int ni = 0; ni < 4; ++ni)                                   \
                    acc[mi][ni] = __builtin_amdgcn_mfma_f32_16x16x32_bf16(       \
                        a[mi], b[ni], acc[mi][ni], 0, 0, 0);                     \
        } while (0)

    const int nt = K / 32;

    STAGE(0, 0);
    STAGE(1, 32);
    STAGE(2, 64);

    int t = 0;
    for (; t <= nt - 4; ++t) {
        WAITV8(); BAR();
        COMPUTE(t & 3);
        STAGE((t + 3) & 3, (t + 3) * 32);
    }
    WAITV8(); BAR(); COMPUTE(t & 3); ++t;
    WAITV4(); BAR(); COMPUTE(t & 3); ++t;
    WAITV0(); BAR(); COMPUTE(t & 3);

    #undef STAGE
    #undef COMPUTE

    __syncthreads();

    float* stf = (float*)smem;
    #pragma unroll
    for (int mi = 0; mi < 4; ++mi)
        #pragma unroll
        for (int j = 0; j < 4; ++j) {
            const int r = wm + mi * 16 + fq * 4 + j;
            #pragma unroll
            for (int ni = 0; ni < 4; ++ni) {
                const int c = wn + ni * 16 + fr;
                stf[r * 128 + c] = acc[mi][ni][j] + bias[n0 + c];
            }
        }
    __syncthreads();
    #pragma unroll
    for (int i = 0; i < 16; ++i) {
        const int ch = i * 256 + tid;
        const int row = ch >> 5;
        const int coff = (ch & 31) * 4;
        const int gm = m0 + row;
        if (gm < M)
            *(float4*)(C + (size_t)gm * N + n0 + coff) =
                *(const float4*)(stf + row * 128 + coff);
    }
}

// ---------------------------------------------------------------------------
// Merged attention: blocks [0, 1024) = cls stage 1; [1024, 1536) = patch.
// ---------------------------------------------------------------------------
#define NCHUNK 64
#define CLS_ROWS 129             // ceil(8193/64)
#define CLS_BLOCKS (B_ * H_ * NCHUNK)   // 1024
#define PQT 256
#define PATCH_BLOCKS (B_ * H_ * (L_ / PQT))  // 512

__global__ __launch_bounds__(256) void attn_fused(
    const u16* __restrict__ qkvb, float* __restrict__ part,
    u16* __restrict__ attnb)
{
    __shared__ __align__(16) u16 sbuf[272 * 64];   // patch K/V window (34.8 KB)
    __shared__ float kcvc[128];
    __shared__ float sm4[4], sl4[4];

    const int blk = blockIdx.x;

    if (blk < CLS_BLOCKS) {
        // ---------------- CLS stage 1 ----------------
        const int bh = blk >> 6, ch = blk & 63;
        const int b = bh >> 3, h = bh & 7;
        const int wid = threadIdx.x >> 6, lane = threadIdx.x & 63;
        const size_t base = (size_t)b * S_ * QKV_COLS;

        const float q = bf2f(qkvb[base + h * D_ + lane]);

        const int lo = ch * CLS_ROWS;
        const int hi = (lo + CLS_ROWS < S_) ? lo + CLS_ROWS : S_;

        float m = -1e30f, lsum = 0.f, acc = 0.f;
        for (int j = lo + wid; j < hi; j += 4) {
            const size_t roff = base + (size_t)j * QKV_COLS;
            float t = q * bf2f(qkvb[roff + E_ + h * D_ + lane]);
            #pragma unroll
            for (int o = 32; o; o >>= 1) t += __shfl_xor(t, o, 64);
            t *= SCALE;
            const float mn = fmaxf(m, t);
            const float corr = __expf(m - mn);
            const float p = __expf(t - mn);
            lsum = lsum * corr + p;
            acc = acc * corr + p * bf2f(qkvb[roff + 2 * E_ + h * D_ + lane]);
            m = mn;
        }

        float* sacc = (float*)sbuf;
        if (lane == 0) { sm4[wid] = m; sl4[wid] = lsum; }
        sacc[wid * 64 + lane] = acc;
        __syncthreads();
        if (wid == 0) {
            const float gm = fmaxf(fmaxf(sm4[0], sm4[1]), fmaxf(sm4[2], sm4[3]));
            float gl = 0.f, ga = 0.f;
            #pragma unroll
            for (int w = 0; w < 4; ++w) {
                const float c = __expf(sm4[w] - gm);
                gl += sl4[w] * c;
                ga += sacc[w * 64 + lane] * c;
            }
            float* pp = part + ((size_t)bh * NCHUNK + ch) * 66;
            if (lane == 0) { pp[0] = gm; pp[1] = gl; }
            pp[2 + lane] = ga;
        }
        return;
    }

    // ---------------- patch attention ----------------
    const int pblk = blk - CLS_BLOCKS;
    const int qt = pblk & 31;
    const int h = (pblk >> 5) & 7;
    const int b = pblk >> 8;
    const int l0 = qt * PQT;
    const size_t base = (size_t)b * S_ * QKV_COLS;
    const int hoff = h * D_;

    u16* kv = sbuf;
    float* kc = kcvc;
    float* vc = kcvc + 64;

    const int t = threadIdx.x;

    if (t < 64) kc[t] = bf2f(qkvb[base + E_ + hoff + t]);
    else if (t < 128) vc[t - 64] = bf2f(qkvb[base + 2 * E_ + hoff + (t - 64)]);

    #pragma unroll
    for (int i = 0; i < 9; ++i) {
        const int s = i * 256 + t;
        if (s < 272 * 8) {
            const int r = s >> 3, c = s & 7;
            const int lg = l0 - 8 + r;
            u16x8 v = {};
            if (lg >= 0 && lg < L_)
                v = *(const u16x8*)(qkvb + base + (size_t)(1 + lg) * QKV_COLS + E_ + hoff + c * 8);
            *(u16x8*)(kv + r * 64 + ((c ^ (r & 7)) * 8)) = v;
        }
    }
    __syncthreads();

    const int l = l0 + t;
    const size_t qrow = base + (size_t)(1 + l) * QKV_COLS + hoff;

    float s[10];
    #pragma unroll
    for (int w = 0; w < 10; ++w) s[w] = 0.f;

    #pragma unroll
    for (int c = 0; c < 8; ++c) {
        const u16x8 qv = *(const u16x8*)(qkvb + qrow + c * 8);
        float qf[8];
        #pragma unroll
        for (int i = 0; i < 8; ++i) qf[i] = bf2f(qv[i]);
        #pragma unroll
        for (int i = 0; i < 8; ++i) s[0] += qf[i] * kc[c * 8 + i];
        #pragma unroll
        for (int w = 0; w < 9; ++w) {
            const int kr = t + 2 * w;
            const u16x8 kk = *(const u16x8*)(kv + kr * 64 + ((c ^ (kr & 7)) * 8));
            #pragma unroll
            for (int i = 0; i < 8; ++i) s[1 + w] += qf[i] * bf2f(kk[i]);
        }
    }

    s[0] *= SCALE;
    #pragma unroll
    for (int w = 0; w < 9; ++w) {
        const int lp = l + 2 * w - 8;
        s[1 + w] = (lp >= 0 && lp < L_) ? s[1 + w] * SCALE : -1e30f;
    }
    float m = s[0];
    #pragma unroll
    for (int w = 1; w < 10; ++w) m = fmaxf(m, s[w]);
    float sum = 0.f;
    #pragma unroll
    for (int w = 0; w < 10; ++w) { s[w] = __expf(s[w] - m); sum += s[w]; }
    const float rsum = 1.0f / sum;

    __syncthreads();
    #pragma unroll
    for (int i = 0; i < 9; ++i) {
        const int sl = i * 256 + t;
        if (sl < 272 * 8) {
            const int r = sl >> 3, c = sl & 7;
            const int lg = l0 - 8 + r;
            u16x8 v = {};
            if (lg >= 0 && lg < L_)
                v = *(const u16x8*)(qkvb + base + (size_t)(1 + lg) * QKV_COLS + 2 * E_ + hoff + c * 8);
            *(u16x8*)(kv + r * 64 + ((c ^ (r & 7)) * 8)) = v;
        }
    }
    __syncthreads();

    const size_t orow = (size_t)(b * S_ + 1 + l) * E_ + hoff;
    #pragma unroll
    for (int c = 0; c < 8; ++c) {
        float acc[8];
        #pragma unroll
        for (int i = 0; i < 8; ++i) acc[i] = s[0] * vc[c * 8 + i];
        #pragma unroll
        for (int w = 0; w < 9; ++w) {
            const int vr = t + 2 * w;
            const u16x8 vv = *(const u16x8*)(kv + vr * 64 + ((c ^ (vr & 7)) * 8));
            #pragma unroll
            for (int i = 0; i < 8; ++i) acc[i] += s[1 + w] * bf2f(vv[i]);
        }
        u16x8 o;
        #pragma unroll
        for (int i = 0; i < 8; ++i) o[i] = f2bf(acc[i] * rsum);
        *(u16x8*)(attnb + orow + c * 8) = o;
    }
}

// ---------------------------------------------------------------------------
// CLS stage 2: combine 64 chunks per (b,h). 16 blocks x 64 threads.
// ---------------------------------------------------------------------------
__global__ __launch_bounds__(64) void cls_attn_stage2(
    const float* __restrict__ part, u16* __restrict__ attnb)
{
    const int bh = blockIdx.x;
    const int lane = threadIdx.x;
    const int b = bh >> 3, h = bh & 7;
    float gm = -1e30f;
    for (int c = 0; c < NCHUNK; ++c)
        gm = fmaxf(gm, part[((size_t)bh * NCHUNK + c) * 66]);
    float gl = 0.f, ga = 0.f;
    for (int c = 0; c < NCHUNK; ++c) {
        const float* pp = part + ((size_t)bh * NCHUNK + c) * 66;
        const float w = __expf(pp[0] - gm);
        gl += pp[1] * w;
        ga += pp[2 + lane] * w;
    }
    attnb[(size_t)(b * S_) * E_ + h * D_ + lane] = f2bf(ga / gl);
}

// ---------------------------------------------------------------------------
// Launch
// ---------------------------------------------------------------------------
extern "C" void kernel_launch(void* const* d_in, const int* in_sizes, int n_in,
                              void* d_out, int out_size, void* d_ws, size_t ws_size,
                              hipStream_t stream)
{
    const float* x      = (const float*)d_in[0];
    const int*   coords = (const int*)  d_in[1];
    const float* w_qkv  = (const float*)d_in[2];
    const float* b_qkv  = (const float*)d_in[3];
    const float* w_out  = (const float*)d_in[4];
    const float* b_out  = (const float*)d_in[5];
    float* out = (float*)d_out;

    // workspace layout
    u16*   qkvb  = (u16*)d_ws;                                // M_ROWS x 1536 bf16
    u16*   attnb = qkvb + (size_t)M_ROWS * QKV_COLS;          // M_PAD x 512 bf16
    u16*   wqb   = attnb + (size_t)M_PAD * E_;                // 1536 x 512
    u16*   wob   = wqb + (size_t)QKV_COLS * E_;               // 512 x 512
    float* part  = (float*)(wob + (size_t)E_ * E_);           // 16*64*66 floats
    float2* tab  = (float2*)(part + (size_t)16 * NCHUNK * 66);// B*L*32 float2 (4 MB)

    // 1. fused prep
    prep_kernel<<<(PREP_TOTAL + 255) / 256, 256, 0, stream>>>(
        w_qkv, w_out, coords, wqb, wob, tab, attnb);

    // 2. QKV projection (A from fp32 x) + fused RoPE, 8-wave blocks
    {
        dim3 grid(QKV_COLS / 128, M_PAD / 128);   // 12 x 129
        gemm_qkv_fused<<<grid, 512, 0, stream>>>(
            x, wqb, b_qkv, qkvb, tab, M_ROWS, QKV_COLS, E_);
    }

    // 3. merged CLS stage1 + patch attention
    attn_fused<<<CLS_BLOCKS + PATCH_BLOCKS, 256, 0, stream>>>(qkvb, part, attnb);

    // 4. CLS stage 2
    cls_attn_stage2<<<B_ * H_, 64, 0, stream>>>(part, attnb);

    // 5. Output projection (fp32 out)
    {
        dim3 grid(E_ / 128, M_PAD / 128);
        gemm_out_128<<<grid, 256, 0, stream>>>(
            attnb, wob, b_out, out, M_ROWS, E_, E_);
    }
}

// Round 18
// 135.082 us; speedup vs baseline: 1.4287x; 1.0583x over previous
//
#include <hip/hip_runtime.h>
#include <math.h>

// Problem constants
#define B_ 2
#define S_ 8193
#define L_ 8192
#define E_ 512
#define H_ 8
#define D_ 64
#define QKV_COLS 1536   // 3*E
#define SCALE 0.125f
#define M_ROWS 16386    // B*S
#define M_PAD 16512     // round up to 128

typedef unsigned short u16;
typedef __attribute__((ext_vector_type(8))) short bf16x8;
typedef __attribute__((ext_vector_type(8))) unsigned short u16x8;
typedef __attribute__((ext_vector_type(4))) float f32x4;

__device__ __forceinline__ u16 f2bf(float f) {
    unsigned u = __float_as_uint(f);
    unsigned r = (u + 0x7fffu + ((u >> 16) & 1u)) >> 16;   // RNE
    return (u16)r;
}
__device__ __forceinline__ float bf2f(u16 h) {
    return __uint_as_float((unsigned)h << 16);
}

__device__ __forceinline__ void gload_lds16(const void* g, void* l) {
    __builtin_amdgcn_global_load_lds(
        (const __attribute__((address_space(1))) void*)g,
        (__attribute__((address_space(3))) void*)l, 16, 0, 0);
}

#define WAITV0() asm volatile("s_waitcnt vmcnt(0)" ::: "memory")
#define BAR()    __builtin_amdgcn_s_barrier()

// ---------------------------------------------------------------------------
// Fused prep: x convert | wqb convert | wob convert | rope table | pad zero.
// ---------------------------------------------------------------------------
#define PREP_W0 (M_PAD * E_ / 4)               // x quads (zero-padded rows)
#define PREP_W1 (QKV_COLS * E_ / 4)            // w_qkv quads
#define PREP_W2 (E_ * E_ / 4)                  // w_out quads
#define PREP_W3 (B_ * L_ * 32)                 // rope entries
#define PREP_W4 ((M_PAD - M_ROWS) * E_ / 8)    // attnb pad chunks
#define PREP_TOTAL (PREP_W0 + PREP_W1 + PREP_W2 + PREP_W3 + PREP_W4)

__global__ __launch_bounds__(256) void prep_kernel(
    const float* __restrict__ x,
    const float* __restrict__ w_qkv, const float* __restrict__ w_out,
    const int* __restrict__ coords,
    u16* __restrict__ xb, u16* __restrict__ wqb, u16* __restrict__ wob,
    float2* __restrict__ tab, u16* __restrict__ attnb)
{
    long i = (long)blockIdx.x * 256 + threadIdx.x;
    if (i < PREP_W0) {
        const long row = i >> 7;               // 128 quads per 512-col row
        ushort4 o = make_ushort4(0, 0, 0, 0);
        if (row < M_ROWS) {
            const float4 v = *(const float4*)(x + i * 4);
            o.x = f2bf(v.x); o.y = f2bf(v.y); o.z = f2bf(v.z); o.w = f2bf(v.w);
        }
        *(ushort4*)(xb + i * 4) = o;
        return;
    }
    i -= PREP_W0;
    if (i < PREP_W1) {
        const float4 v = *(const float4*)(w_qkv + i * 4);
        ushort4 o = { f2bf(v.x), f2bf(v.y), f2bf(v.z), f2bf(v.w) };
        *(ushort4*)(wqb + i * 4) = o;
        return;
    }
    i -= PREP_W1;
    if (i < PREP_W2) {
        const float4 v = *(const float4*)(w_out + i * 4);
        ushort4 o = { f2bf(v.x), f2bf(v.y), f2bf(v.z), f2bf(v.w) };
        *(ushort4*)(wob + i * 4) = o;
        return;
    }
    i -= PREP_W2;
    if (i < PREP_W3) {
        const int p2 = (int)i & 31;
        const int bl = (int)i >> 5;
        const float coord = (float)coords[(size_t)bl * 2 + (p2 >> 4)] * 1e-5f;
        const float inv = exp2f(-0.83048202372184f * (float)(p2 & 15));
        float sn, cs;
        __sincosf(coord * inv, &sn, &cs);
        tab[i] = make_float2(cs, sn);
        return;
    }
    i -= PREP_W3;
    if (i < PREP_W4) {
        u16x8 z = {};
        *(u16x8*)(attnb + (size_t)M_ROWS * E_ + i * 8) = z;
    }
}

// ---------------------------------------------------------------------------
// Unified bf16 GEMM, 512 threads / 8 waves (2M x 4N, wave out 64x32),
// 128x128 tile, BK=32, K=512 (16 tiles). Ring-2 LDS (32 KB), pure
// global_load_lds for A and B. ORDER-ROBUST pipeline (R16 pattern):
// loads for tile t+1 issued right after the barrier, drained by WAITV0 at
// the NEXT iteration top -> full compute phase of overlap, no ordering
// assumptions on load retirement. One barrier per step.
// Swizzle (R9 zero-conflict pair): LDS position (row r, phys chunk p)
// holds global chunk p ^ ((r>>1)&3); read phys = fq ^ ((fr>>1)&3).
// MODE 0: C fp32 + bias (epilogue staged in 64-row halves).
// MODE 1: C bf16 + bias + RoPE (table), 32 KB staging.
// ---------------------------------------------------------------------------
template <int MODE>
__global__ __launch_bounds__(512, 6) void gemm512(
    const u16* __restrict__ A, const u16* __restrict__ W,
    const float* __restrict__ bias, void* __restrict__ Cv,
    const float2* __restrict__ tab, int M, int N)
{
    // 32 KB: A rings @ 0/4096 u16, B rings @ 8192/12288 u16
    __shared__ __align__(16) u16 smem[16384];

    // XCD-aware bijective swizzle (m204)
    const int nwg = gridDim.x * gridDim.y;
    const int orig = blockIdx.y * gridDim.x + blockIdx.x;
    const int qq = nwg >> 3, rr = nwg & 7;
    const int xcd = orig & 7, off = orig >> 3;
    const int wgid = (xcd < rr ? xcd * (qq + 1) : rr * (qq + 1) + (xcd - rr) * qq) + off;
    const int m0 = (wgid / gridDim.x) * 128;
    const int n0 = (wgid % gridDim.x) * 128;

    const int tid  = threadIdx.x;
    const int wid  = tid >> 6;
    const int lane = tid & 63;
    const int wm = (wid >> 2) * 64;    // 2 M-waves
    const int wn = (wid & 3) * 32;     // 4 N-waves
    const int fr = lane & 15;
    const int fq = lane >> 4;          // 0..3
    const int sfq = (fq ^ ((fr >> 1) & 3)) * 8;   // swizzled read chunk (R9, 0-conflict)

    // loader: 1 chunk/thread/matrix. thread tid -> row tid>>2, phys chunk tid&3.
    const int arow = tid >> 2;                              // 0..127
    const int agch = ((tid & 3) ^ ((arow >> 1) & 3)) * 8;   // pre-swizzled src chunk
    const u16* ga = A + (size_t)(m0 + arow) * 512 + agch;
    const u16* gw = W + (size_t)(n0 + arow) * 512 + agch;

    f32x4 acc[4][2] = {};

    // LDS dest passed wave-uniform; HW adds lane*16B -> lane l of wave w
    // lands at rb*4096 + w*512 + l*8 = position (row tid>>2, phys tid&3).
    #define STAGE(rb, kt)                                                       \
        do {                                                                    \
            gload_lds16(ga + (kt) * 32, smem + (rb) * 4096 + wid * 512);        \
            gload_lds16(gw + (kt) * 32, smem + 8192 + (rb) * 4096 + wid * 512); \
        } while (0)

    #define COMPUTE(rb)                                                         \
        do {                                                                    \
            const u16* as_ = smem + (rb) * 4096;                                \
            const u16* bs_ = smem + 8192 + (rb) * 4096;                         \
            bf16x8 a[4], b[2];                                                  \
            _Pragma("unroll")                                                   \
            for (int mi = 0; mi < 4; ++mi)                                      \
                a[mi] = *(const bf16x8*)(as_ + (wm + mi * 16 + fr) * 32 + sfq); \
            _Pragma("unroll")                                                   \
            for (int ni = 0; ni < 2; ++ni)                                      \
                b[ni] = *(const bf16x8*)(bs_ + (wn + ni * 16 + fr) * 32 + sfq); \
            _Pragma("unroll")                                                   \
            for (int mi = 0; mi < 4; ++mi)                                      \
                _Pragma("unroll")                                               \
                for (int ni = 0; ni < 2; ++ni)                                  \
                    acc[mi][ni] = __builtin_amdgcn_mfma_f32_16x16x32_bf16(      \
                        a[mi], b[ni], acc[mi][ni], 0, 0, 0);                    \
        } while (0)

    // prologue: tile 0
    STAGE(0, 0);

    for (int t = 0; t < 16; ++t) {
        WAITV0();                 // this wave's outstanding loads (tile t) landed
        BAR();                    // ...for ALL waves; also: all waves done
                                  // reading buf (t+1)&1 (their COMPUTE(t-1))
        if (t + 1 < 16) STAGE((t + 1) & 1, t + 1);   // fly during COMPUTE(t)
        COMPUTE(t & 1);
    }

    #undef STAGE
    #undef COMPUTE

    __syncthreads();   // release LDS ring; reuse as C staging

    if (MODE == 1) {
        // bf16 + RoPE epilogue, full 128x128 u16 tile (32 KB)
        u16* st = smem;
        const bool rope_blk = (n0 < 2 * E_);
        #pragma unroll
        for (int mi = 0; mi < 4; ++mi) {
            #pragma unroll
            for (int j = 0; j < 4; ++j) {
                const int row = wm + mi * 16 + fq * 4 + j;
                const int gm = m0 + row;
                int b = 0, s = gm;
                if (gm >= S_) { b = 1; s = gm - S_; }
                const bool rot = rope_blk && (gm < M) && (s > 0);
                const float2* trow = tab + ((size_t)(b * L_ + (s - 1)) << 5);
                #pragma unroll
                for (int ni = 0; ni < 2; ++ni) {
                    const int col = wn + ni * 16 + fr;
                    const int gn = n0 + col;
                    float v = acc[mi][ni][j] + bias[gn];
                    const float partner = __shfl_xor(v, 1, 64);  // gn^1 in lane^1
                    if (rot) {
                        const float2 tt = trow[(gn & 63) >> 1];
                        v = (gn & 1) ? (v * tt.x + partner * tt.y)
                                     : (v * tt.x - partner * tt.y);
                    }
                    st[row * 128 + col] = f2bf(v);
                }
            }
        }
        __syncthreads();
        u16* C = (u16*)Cv;
        #pragma unroll
        for (int i = 0; i < 4; ++i) {
            const int slot = i * 512 + tid;
            const int row = slot >> 4;
            const int coff = (slot & 15) * 8;
            const int gm = m0 + row;
            if (gm < M)
                *(u16x8*)(C + (size_t)gm * N + n0 + coff) =
                    *(const u16x8*)(st + row * 128 + coff);
        }
    } else {
        // fp32 epilogue in 64-row halves (32 KB each)
        float* stf = (float*)smem;
        float* C = (float*)Cv;
        #pragma unroll
        for (int h = 0; h < 2; ++h) {
            if ((wid >> 2) == h) {
                #pragma unroll
                for (int mi = 0; mi < 4; ++mi)
                    #pragma unroll
                    for (int j = 0; j < 4; ++j) {
                        const int lrow = mi * 16 + fq * 4 + j;   // 0..63
                        #pragma unroll
                        for (int ni = 0; ni < 2; ++ni) {
                            const int col = wn + ni * 16 + fr;
                            stf[lrow * 128 + col] = acc[mi][ni][j] + bias[n0 + col];
                        }
                    }
            }
            __syncthreads();
            #pragma unroll
            for (int i = 0; i < 4; ++i) {
                const int slot = i * 512 + tid;
                const int row = slot >> 5;           // 0..63
                const int coff = (slot & 31) * 4;
                const int gm = m0 + h * 64 + row;
                if (gm < M)
                    *(float4*)(C + (size_t)gm * N + n0 + coff) =
                        *(const float4*)(stf + row * 128 + coff);
            }
            __syncthreads();
        }
    }
}

// ---------------------------------------------------------------------------
// Merged attention: blocks [0, 1024) = cls stage 1; [1024, 1536) = patch.
// (R16 verbatim — passed.)
// ---------------------------------------------------------------------------
#define NCHUNK 64
#define CLS_ROWS 129             // ceil(8193/64)
#define CLS_BLOCKS (B_ * H_ * NCHUNK)   // 1024
#define PQT 256
#define PATCH_BLOCKS (B_ * H_ * (L_ / PQT))  // 512

__global__ __launch_bounds__(256) void attn_fused(
    const u16* __restrict__ qkvb, float* __restrict__ part,
    u16* __restrict__ attnb)
{
    __shared__ __align__(16) u16 sbuf[272 * 64];   // patch K/V window (34.8 KB)
    __shared__ float kcvc[128];
    __shared__ float sm4[4], sl4[4];

    const int blk = blockIdx.x;

    if (blk < CLS_BLOCKS) {
        // ---------------- CLS stage 1 ----------------
        const int bh = blk >> 6, ch = blk & 63;
        const int b = bh >> 3, h = bh & 7;
        const int wid = threadIdx.x >> 6, lane = threadIdx.x & 63;
        const size_t base = (size_t)b * S_ * QKV_COLS;

        const float q = bf2f(qkvb[base + h * D_ + lane]);

        const int lo = ch * CLS_ROWS;
        const int hi = (lo + CLS_ROWS < S_) ? lo + CLS_ROWS : S_;

        float m = -1e30f, lsum = 0.f, acc = 0.f;
        for (int j = lo + wid; j < hi; j += 4) {
            const size_t roff = base + (size_t)j * QKV_COLS;
            float t = q * bf2f(qkvb[roff + E_ + h * D_ + lane]);
            #pragma unroll
            for (int o = 32; o; o >>= 1) t += __shfl_xor(t, o, 64);
            t *= SCALE;
            const float mn = fmaxf(m, t);
            const float corr = __expf(m - mn);
            const float p = __expf(t - mn);
            lsum = lsum * corr + p;
            acc = acc * corr + p * bf2f(qkvb[roff + 2 * E_ + h * D_ + lane]);
            m = mn;
        }

        float* sacc = (float*)sbuf;
        if (lane == 0) { sm4[wid] = m; sl4[wid] = lsum; }
        sacc[wid * 64 + lane] = acc;
        __syncthreads();
        if (wid == 0) {
            const float gm = fmaxf(fmaxf(sm4[0], sm4[1]), fmaxf(sm4[2], sm4[3]));
            float gl = 0.f, ga = 0.f;
            #pragma unroll
            for (int w = 0; w < 4; ++w) {
                const float c = __expf(sm4[w] - gm);
                gl += sl4[w] * c;
                ga += sacc[w * 64 + lane] * c;
            }
            float* pp = part + ((size_t)bh * NCHUNK + ch) * 66;
            if (lane == 0) { pp[0] = gm; pp[1] = gl; }
            pp[2 + lane] = ga;
        }
        return;
    }

    // ---------------- patch attention ----------------
    const int pblk = blk - CLS_BLOCKS;
    const int qt = pblk & 31;
    const int h = (pblk >> 5) & 7;
    const int b = pblk >> 8;
    const int l0 = qt * PQT;
    const size_t base = (size_t)b * S_ * QKV_COLS;
    const int hoff = h * D_;

    u16* kv = sbuf;
    float* kc = kcvc;
    float* vc = kcvc + 64;

    const int t = threadIdx.x;

    if (t < 64) kc[t] = bf2f(qkvb[base + E_ + hoff + t]);
    else if (t < 128) vc[t - 64] = bf2f(qkvb[base + 2 * E_ + hoff + (t - 64)]);

    #pragma unroll
    for (int i = 0; i < 9; ++i) {
        const int s = i * 256 + t;
        if (s < 272 * 8) {
            const int r = s >> 3, c = s & 7;
            const int lg = l0 - 8 + r;
            u16x8 v = {};
            if (lg >= 0 && lg < L_)
                v = *(const u16x8*)(qkvb + base + (size_t)(1 + lg) * QKV_COLS + E_ + hoff + c * 8);
            *(u16x8*)(kv + r * 64 + ((c ^ (r & 7)) * 8)) = v;
        }
    }
    __syncthreads();

    const int l = l0 + t;
    const size_t qrow = base + (size_t)(1 + l) * QKV_COLS + hoff;

    float s[10];
    #pragma unroll
    for (int w = 0; w < 10; ++w) s[w] = 0.f;

    #pragma unroll
    for (int c = 0; c < 8; ++c) {
        const u16x8 qv = *(const u16x8*)(qkvb + qrow + c * 8);
        float qf[8];
        #pragma unroll
        for (int i = 0; i < 8; ++i) qf[i] = bf2f(qv[i]);
        #pragma unroll
        for (int i = 0; i < 8; ++i) s[0] += qf[i] * kc[c * 8 + i];
        #pragma unroll
        for (int w = 0; w < 9; ++w) {
            const int kr = t + 2 * w;
            const u16x8 kk = *(const u16x8*)(kv + kr * 64 + ((c ^ (kr & 7)) * 8));
            #pragma unroll
            for (int i = 0; i < 8; ++i) s[1 + w] += qf[i] * bf2f(kk[i]);
        }
    }

    s[0] *= SCALE;
    #pragma unroll
    for (int w = 0; w < 9; ++w) {
        const int lp = l + 2 * w - 8;
        s[1 + w] = (lp >= 0 && lp < L_) ? s[1 + w] * SCALE : -1e30f;
    }
    float m = s[0];
    #pragma unroll
    for (int w = 1; w < 10; ++w) m = fmaxf(m, s[w]);
    float sum = 0.f;
    #pragma unroll
    for (int w = 0; w < 10; ++w) { s[w] = __expf(s[w] - m); sum += s[w]; }
    const float rsum = 1.0f / sum;

    __syncthreads();
    #pragma unroll
    for (int i = 0; i < 9; ++i) {
        const int sl = i * 256 + t;
        if (sl < 272 * 8) {
            const int r = sl >> 3, c = sl & 7;
            const int lg = l0 - 8 + r;
            u16x8 v = {};
            if (lg >= 0 && lg < L_)
                v = *(const u16x8*)(qkvb + base + (size_t)(1 + lg) * QKV_COLS + 2 * E_ + hoff + c * 8);
            *(u16x8*)(kv + r * 64 + ((c ^ (r & 7)) * 8)) = v;
        }
    }
    __syncthreads();

    const size_t orow = (size_t)(b * S_ + 1 + l) * E_ + hoff;
    #pragma unroll
    for (int c = 0; c < 8; ++c) {
        float acc[8];
        #pragma unroll
        for (int i = 0; i < 8; ++i) acc[i] = s[0] * vc[c * 8 + i];
        #pragma unroll
        for (int w = 0; w < 9; ++w) {
            const int vr = t + 2 * w;
            const u16x8 vv = *(const u16x8*)(kv + vr * 64 + ((c ^ (vr & 7)) * 8));
            #pragma unroll
            for (int i = 0; i < 8; ++i) acc[i] += s[1 + w] * bf2f(vv[i]);
        }
        u16x8 o;
        #pragma unroll
        for (int i = 0; i < 8; ++i) o[i] = f2bf(acc[i] * rsum);
        *(u16x8*)(attnb + orow + c * 8) = o;
    }
}

// ---------------------------------------------------------------------------
// CLS stage 2: combine 64 chunks per (b,h). 16 blocks x 64 threads.
// ---------------------------------------------------------------------------
__global__ __launch_bounds__(64) void cls_attn_stage2(
    const float* __restrict__ part, u16* __restrict__ attnb)
{
    const int bh = blockIdx.x;
    const int lane = threadIdx.x;
    const int b = bh >> 3, h = bh & 7;
    float gm = -1e30f;
    for (int c = 0; c < NCHUNK; ++c)
        gm = fmaxf(gm, part[((size_t)bh * NCHUNK + c) * 66]);
    float gl = 0.f, ga = 0.f;
    for (int c = 0; c < NCHUNK; ++c) {
        const float* pp = part + ((size_t)bh * NCHUNK + c) * 66;
        const float w = __expf(pp[0] - gm);
        gl += pp[1] * w;
        ga += pp[2 + lane] * w;
    }
    attnb[(size_t)(b * S_) * E_ + h * D_ + lane] = f2bf(ga / gl);
}

// ---------------------------------------------------------------------------
// Launch
// ---------------------------------------------------------------------------
extern "C" void kernel_launch(void* const* d_in, const int* in_sizes, int n_in,
                              void* d_out, int out_size, void* d_ws, size_t ws_size,
                              hipStream_t stream)
{
    const float* x      = (const float*)d_in[0];
    const int*   coords = (const int*)  d_in[1];
    const float* w_qkv  = (const float*)d_in[2];
    const float* b_qkv  = (const float*)d_in[3];
    const float* w_out  = (const float*)d_in[4];
    const float* b_out  = (const float*)d_in[5];
    float* out = (float*)d_out;

    // workspace layout
    u16*   qkvb  = (u16*)d_ws;                                // M_ROWS x 1536 bf16
    u16*   attnb = qkvb + (size_t)M_ROWS * QKV_COLS;          // M_PAD x 512 bf16
    u16*   xb    = attnb + (size_t)M_PAD * E_;                // M_PAD x 512 bf16
    u16*   wqb   = xb + (size_t)M_PAD * E_;                   // 1536 x 512
    u16*   wob   = wqb + (size_t)QKV_COLS * E_;               // 512 x 512
    float* part  = (float*)(wob + (size_t)E_ * E_);           // 16*64*66 floats
    float2* tab  = (float2*)(part + (size_t)16 * NCHUNK * 66);// B*L*32 float2 (4 MB)

    // 1. fused prep (x + weights to bf16, rope table, pad zero)
    prep_kernel<<<(PREP_TOTAL + 255) / 256, 256, 0, stream>>>(
        x, w_qkv, w_out, coords, xb, wqb, wob, tab, attnb);

    // 2. QKV projection + fused RoPE, 512-thread order-robust pipeline
    {
        dim3 grid(QKV_COLS / 128, M_PAD / 128);   // 12 x 129
        gemm512<1><<<grid, 512, 0, stream>>>(
            xb, wqb, b_qkv, qkvb, tab, M_ROWS, QKV_COLS);
    }

    // 3. merged CLS stage1 + patch attention
    attn_fused<<<CLS_BLOCKS + PATCH_BLOCKS, 256, 0, stream>>>(qkvb, part, attnb);

    // 4. CLS stage 2
    cls_attn_stage2<<<B_ * H_, 64, 0, stream>>>(part, attnb);

    // 5. Output projection (fp32 out), same 512-thread pipeline
    {
        dim3 grid(E_ / 128, M_PAD / 128);         // 4 x 129
        gemm512<0><<<grid, 512, 0, stream>>>(
            attnb, wob, b_out, out, nullptr, M_ROWS, E_);
    }
}

// Round 19
// 120.047 us; speedup vs baseline: 1.6076x; 1.1252x over previous
//
#include <hip/hip_runtime.h>
#include <math.h>

// Problem constants
#define B_ 2
#define S_ 8193
#define L_ 8192
#define E_ 512
#define H_ 8
#define D_ 64
#define QKV_COLS 1536   // 3*E
#define SCALE 0.125f
#define M_ROWS 16386    // B*S
#define M_PAD 16512     // round up to 128

typedef unsigned short u16;
typedef __attribute__((ext_vector_type(8))) short bf16x8;
typedef __attribute__((ext_vector_type(8))) unsigned short u16x8;
typedef __attribute__((ext_vector_type(4))) float f32x4;

__device__ __forceinline__ u16 f2bf(float f) {
    unsigned u = __float_as_uint(f);
    unsigned r = (u + 0x7fffu + ((u >> 16) & 1u)) >> 16;   // RNE
    return (u16)r;
}
__device__ __forceinline__ float bf2f(u16 h) {
    return __uint_as_float((unsigned)h << 16);
}

__device__ __forceinline__ void gload_lds16(const void* g, void* l) {
    __builtin_amdgcn_global_load_lds(
        (const __attribute__((address_space(1))) void*)g,
        (__attribute__((address_space(3))) void*)l, 16, 0, 0);
}

#define WAITV0() asm volatile("s_waitcnt vmcnt(0)" ::: "memory")
#define BAR()    __builtin_amdgcn_s_barrier()

// ---------------------------------------------------------------------------
// Fused prep: x convert | wqb convert | wob convert | rope table | pad zero.
// ---------------------------------------------------------------------------
#define PREP_W0 (M_PAD * E_ / 4)               // x quads (zero-padded rows)
#define PREP_W1 (QKV_COLS * E_ / 4)            // w_qkv quads
#define PREP_W2 (E_ * E_ / 4)                  // w_out quads
#define PREP_W3 (B_ * L_ * 32)                 // rope entries
#define PREP_W4 ((M_PAD - M_ROWS) * E_ / 8)    // attnb pad chunks
#define PREP_TOTAL (PREP_W0 + PREP_W1 + PREP_W2 + PREP_W3 + PREP_W4)

__global__ __launch_bounds__(256) void prep_kernel(
    const float* __restrict__ x,
    const float* __restrict__ w_qkv, const float* __restrict__ w_out,
    const int* __restrict__ coords,
    u16* __restrict__ xb, u16* __restrict__ wqb, u16* __restrict__ wob,
    float2* __restrict__ tab, u16* __restrict__ attnb)
{
    long i = (long)blockIdx.x * 256 + threadIdx.x;
    if (i < PREP_W0) {
        const long row = i >> 7;               // 128 quads per 512-col row
        ushort4 o = make_ushort4(0, 0, 0, 0);
        if (row < M_ROWS) {
            const float4 v = *(const float4*)(x + i * 4);
            o.x = f2bf(v.x); o.y = f2bf(v.y); o.z = f2bf(v.z); o.w = f2bf(v.w);
        }
        *(ushort4*)(xb + i * 4) = o;
        return;
    }
    i -= PREP_W0;
    if (i < PREP_W1) {
        const float4 v = *(const float4*)(w_qkv + i * 4);
        ushort4 o = { f2bf(v.x), f2bf(v.y), f2bf(v.z), f2bf(v.w) };
        *(ushort4*)(wqb + i * 4) = o;
        return;
    }
    i -= PREP_W1;
    if (i < PREP_W2) {
        const float4 v = *(const float4*)(w_out + i * 4);
        ushort4 o = { f2bf(v.x), f2bf(v.y), f2bf(v.z), f2bf(v.w) };
        *(ushort4*)(wob + i * 4) = o;
        return;
    }
    i -= PREP_W2;
    if (i < PREP_W3) {
        const int p2 = (int)i & 31;
        const int bl = (int)i >> 5;
        const float coord = (float)coords[(size_t)bl * 2 + (p2 >> 4)] * 1e-5f;
        const float inv = exp2f(-0.83048202372184f * (float)(p2 & 15));
        float sn, cs;
        __sincosf(coord * inv, &sn, &cs);
        tab[i] = make_float2(cs, sn);
        return;
    }
    i -= PREP_W3;
    if (i < PREP_W4) {
        u16x8 z = {};
        *(u16x8*)(attnb + (size_t)M_ROWS * E_ + i * 8) = z;
    }
}

// ---------------------------------------------------------------------------
// Unified bf16 GEMM, 512 threads / 8 waves (R18 verbatim — passed).
// ---------------------------------------------------------------------------
template <int MODE>
__global__ __launch_bounds__(512, 6) void gemm512(
    const u16* __restrict__ A, const u16* __restrict__ W,
    const float* __restrict__ bias, void* __restrict__ Cv,
    const float2* __restrict__ tab, int M, int N)
{
    __shared__ __align__(16) u16 smem[16384];

    const int nwg = gridDim.x * gridDim.y;
    const int orig = blockIdx.y * gridDim.x + blockIdx.x;
    const int qq = nwg >> 3, rr = nwg & 7;
    const int xcd = orig & 7, off = orig >> 3;
    const int wgid = (xcd < rr ? xcd * (qq + 1) : rr * (qq + 1) + (xcd - rr) * qq) + off;
    const int m0 = (wgid / gridDim.x) * 128;
    const int n0 = (wgid % gridDim.x) * 128;

    const int tid  = threadIdx.x;
    const int wid  = tid >> 6;
    const int lane = tid & 63;
    const int wm = (wid >> 2) * 64;
    const int wn = (wid & 3) * 32;
    const int fr = lane & 15;
    const int fq = lane >> 4;
    const int sfq = (fq ^ ((fr >> 1) & 3)) * 8;

    const int arow = tid >> 2;
    const int agch = ((tid & 3) ^ ((arow >> 1) & 3)) * 8;
    const u16* ga = A + (size_t)(m0 + arow) * 512 + agch;
    const u16* gw = W + (size_t)(n0 + arow) * 512 + agch;

    f32x4 acc[4][2] = {};

    #define STAGE(rb, kt)                                                       \
        do {                                                                    \
            gload_lds16(ga + (kt) * 32, smem + (rb) * 4096 + wid * 512);        \
            gload_lds16(gw + (kt) * 32, smem + 8192 + (rb) * 4096 + wid * 512); \
        } while (0)

    #define COMPUTE(rb)                                                         \
        do {                                                                    \
            const u16* as_ = smem + (rb) * 4096;                                \
            const u16* bs_ = smem + 8192 + (rb) * 4096;                         \
            bf16x8 a[4], b[2];                                                  \
            _Pragma("unroll")                                                   \
            for (int mi = 0; mi < 4; ++mi)                                      \
                a[mi] = *(const bf16x8*)(as_ + (wm + mi * 16 + fr) * 32 + sfq); \
            _Pragma("unroll")                                                   \
            for (int ni = 0; ni < 2; ++ni)                                      \
                b[ni] = *(const bf16x8*)(bs_ + (wn + ni * 16 + fr) * 32 + sfq); \
            _Pragma("unroll")                                                   \
            for (int mi = 0; mi < 4; ++mi)                                      \
                _Pragma("unroll")                                               \
                for (int ni = 0; ni < 2; ++ni)                                  \
                    acc[mi][ni] = __builtin_amdgcn_mfma_f32_16x16x32_bf16(      \
                        a[mi], b[ni], acc[mi][ni], 0, 0, 0);                    \
        } while (0)

    STAGE(0, 0);

    for (int t = 0; t < 16; ++t) {
        WAITV0();
        BAR();
        if (t + 1 < 16) STAGE((t + 1) & 1, t + 1);
        COMPUTE(t & 1);
    }

    #undef STAGE
    #undef COMPUTE

    __syncthreads();

    if (MODE == 1) {
        u16* st = smem;
        const bool rope_blk = (n0 < 2 * E_);
        #pragma unroll
        for (int mi = 0; mi < 4; ++mi) {
            #pragma unroll
            for (int j = 0; j < 4; ++j) {
                const int row = wm + mi * 16 + fq * 4 + j;
                const int gm = m0 + row;
                int b = 0, s = gm;
                if (gm >= S_) { b = 1; s = gm - S_; }
                const bool rot = rope_blk && (gm < M) && (s > 0);
                const float2* trow = tab + ((size_t)(b * L_ + (s - 1)) << 5);
                #pragma unroll
                for (int ni = 0; ni < 2; ++ni) {
                    const int col = wn + ni * 16 + fr;
                    const int gn = n0 + col;
                    float v = acc[mi][ni][j] + bias[gn];
                    const float partner = __shfl_xor(v, 1, 64);
                    if (rot) {
                        const float2 tt = trow[(gn & 63) >> 1];
                        v = (gn & 1) ? (v * tt.x + partner * tt.y)
                                     : (v * tt.x - partner * tt.y);
                    }
                    st[row * 128 + col] = f2bf(v);
                }
            }
        }
        __syncthreads();
        u16* C = (u16*)Cv;
        #pragma unroll
        for (int i = 0; i < 4; ++i) {
            const int slot = i * 512 + tid;
            const int row = slot >> 4;
            const int coff = (slot & 15) * 8;
            const int gm = m0 + row;
            if (gm < M)
                *(u16x8*)(C + (size_t)gm * N + n0 + coff) =
                    *(const u16x8*)(st + row * 128 + coff);
        }
    } else {
        float* stf = (float*)smem;
        float* C = (float*)Cv;
        #pragma unroll
        for (int h = 0; h < 2; ++h) {
            if ((wid >> 2) == h) {
                #pragma unroll
                for (int mi = 0; mi < 4; ++mi)
                    #pragma unroll
                    for (int j = 0; j < 4; ++j) {
                        const int lrow = mi * 16 + fq * 4 + j;
                        #pragma unroll
                        for (int ni = 0; ni < 2; ++ni) {
                            const int col = wn + ni * 16 + fr;
                            stf[lrow * 128 + col] = acc[mi][ni][j] + bias[n0 + col];
                        }
                    }
            }
            __syncthreads();
            #pragma unroll
            for (int i = 0; i < 4; ++i) {
                const int slot = i * 512 + tid;
                const int row = slot >> 5;
                const int coff = (slot & 31) * 4;
                const int gm = m0 + h * 64 + row;
                if (gm < M)
                    *(float4*)(C + (size_t)gm * N + n0 + coff) =
                        *(const float4*)(stf + row * 128 + coff);
            }
            __syncthreads();
        }
    }
}

// ---------------------------------------------------------------------------
// Merged attention v2.
// Blocks [0, 528): CLS stage 1, thread=row two-phase (no serial chains).
//   chunk = 256 rows; stage K swizzled -> per-thread dot from LDS ->
//   block-max tree -> 256 parallel exps -> restage V -> PV lane=d.
// Blocks [528, 1040): patch attention (R16 structure, unchanged).
// ---------------------------------------------------------------------------
#define NCHUNK2 33               // ceil(8193/256)
#define CLS_BLOCKS (B_ * H_ * NCHUNK2)       // 528
#define PQT 256
#define PATCH_BLOCKS (B_ * H_ * (L_ / PQT))  // 512
#define PART_STRIDE ((size_t)16 * 64 * 66)   // keep old part allocation size

__global__ __launch_bounds__(256) void attn_fused(
    const u16* __restrict__ qkvb, float* __restrict__ part,
    u16* __restrict__ attnb)
{
    __shared__ __align__(16) u16 sbuf[272 * 64];   // K/V window (34.8 KB)
    __shared__ float kcvc[128];                    // patch: kc|vc; cls: qs in [0,64)
    __shared__ float red[256];
    __shared__ float esh[256];

    const int blk = blockIdx.x;
    const int t = threadIdx.x;

    if (blk < CLS_BLOCKS) {
        // ---------------- CLS stage 1 v2 ----------------
        const int bh = blk / NCHUNK2, ch = blk % NCHUNK2;
        const int b = bh >> 3, h = bh & 7;
        const size_t base = (size_t)b * S_ * QKV_COLS;
        const int hoff = h * D_;
        const int lo = ch * 256;
        const int wid = t >> 6, lane = t & 63;

        u16* kv = sbuf;                       // 256 x 64 u16
        float* qs = kcvc;                     // 64 floats

        if (t < 64) qs[t] = bf2f(qkvb[base + hoff + t]);

        // stage K rows lo..lo+255 (swizzled chunks, zero OOB)
        #pragma unroll
        for (int i = 0; i < 8; ++i) {
            const int s2 = i * 256 + t;
            const int r = s2 >> 3, c = s2 & 7;
            const int gr = lo + r;
            u16x8 v = {};
            if (gr < S_)
                v = *(const u16x8*)(qkvb + base + (size_t)gr * QKV_COLS + E_ + hoff + c * 8);
            *(u16x8*)(kv + r * 64 + ((c ^ (r & 7)) * 8)) = v;
        }
        __syncthreads();

        // per-thread score for row lo+t
        const bool valid = (lo + t) < S_;
        float sval = 0.f;
        #pragma unroll
        for (int c = 0; c < 8; ++c) {
            const u16x8 kk = *(const u16x8*)(kv + t * 64 + ((c ^ (t & 7)) * 8));
            #pragma unroll
            for (int i = 0; i < 8; ++i) sval += qs[c * 8 + i] * bf2f(kk[i]);
        }
        sval = valid ? sval * SCALE : -1e30f;

        // block max (tree)
        red[t] = sval;
        __syncthreads();
        for (int o = 128; o; o >>= 1) {
            if (t < o) red[t] = fmaxf(red[t], red[t + o]);
            __syncthreads();
        }
        const float m = red[0];
        __syncthreads();

        // parallel exps + sum
        const float e = valid ? __expf(sval - m) : 0.f;
        esh[t] = e;
        red[t] = e;
        __syncthreads();
        for (int o = 128; o; o >>= 1) {
            if (t < o) red[t] += red[t + o];
            __syncthreads();
        }
        const float lsum = red[0];

        // restage V over K (all kv reads for scores are done)
        __syncthreads();
        #pragma unroll
        for (int i = 0; i < 8; ++i) {
            const int s2 = i * 256 + t;
            const int r = s2 >> 3, c = s2 & 7;
            const int gr = lo + r;
            u16x8 v = {};
            if (gr < S_)
                v = *(const u16x8*)(qkvb + base + (size_t)gr * QKV_COLS + 2 * E_ + hoff + c * 8);
            *(u16x8*)(kv + r * 64 + ((c ^ (r & 7)) * 8)) = v;
        }
        __syncthreads();

        // PV: wave wid covers rows wid*64..+63; lane = d
        float acc = 0.f;
        for (int j64 = 0; j64 < 64; ++j64) {
            const int j = (wid << 6) + j64;
            const float ej = esh[j];
            acc += ej * bf2f(kv[j * 64 + (((lane >> 3) ^ (j & 7)) * 8) + (lane & 7)]);
        }
        red[t] = acc;
        __syncthreads();
        if (wid == 0) {
            const float ga = red[lane] + red[64 + lane] + red[128 + lane] + red[192 + lane];
            float* pp = part + ((size_t)bh * NCHUNK2 + ch) * 66;
            if (lane == 0) { pp[0] = m; pp[1] = lsum; }
            pp[2 + lane] = ga;
        }
        return;
    }

    // ---------------- patch attention (unchanged) ----------------
    const int pblk = blk - CLS_BLOCKS;
    const int qt = pblk & 31;
    const int h = (pblk >> 5) & 7;
    const int b = pblk >> 8;
    const int l0 = qt * PQT;
    const size_t base = (size_t)b * S_ * QKV_COLS;
    const int hoff = h * D_;

    u16* kv = sbuf;
    float* kc = kcvc;
    float* vc = kcvc + 64;

    if (t < 64) kc[t] = bf2f(qkvb[base + E_ + hoff + t]);
    else if (t < 128) vc[t - 64] = bf2f(qkvb[base + 2 * E_ + hoff + (t - 64)]);

    #pragma unroll
    for (int i = 0; i < 9; ++i) {
        const int s = i * 256 + t;
        if (s < 272 * 8) {
            const int r = s >> 3, c = s & 7;
            const int lg = l0 - 8 + r;
            u16x8 v = {};
            if (lg >= 0 && lg < L_)
                v = *(const u16x8*)(qkvb + base + (size_t)(1 + lg) * QKV_COLS + E_ + hoff + c * 8);
            *(u16x8*)(kv + r * 64 + ((c ^ (r & 7)) * 8)) = v;
        }
    }
    __syncthreads();

    const int l = l0 + t;
    const size_t qrow = base + (size_t)(1 + l) * QKV_COLS + hoff;

    float s[10];
    #pragma unroll
    for (int w = 0; w < 10; ++w) s[w] = 0.f;

    #pragma unroll
    for (int c = 0; c < 8; ++c) {
        const u16x8 qv = *(const u16x8*)(qkvb + qrow + c * 8);
        float qf[8];
        #pragma unroll
        for (int i = 0; i < 8; ++i) qf[i] = bf2f(qv[i]);
        #pragma unroll
        for (int i = 0; i < 8; ++i) s[0] += qf[i] * kc[c * 8 + i];
        #pragma unroll
        for (int w = 0; w < 9; ++w) {
            const int kr = t + 2 * w;
            const u16x8 kk = *(const u16x8*)(kv + kr * 64 + ((c ^ (kr & 7)) * 8));
            #pragma unroll
            for (int i = 0; i < 8; ++i) s[1 + w] += qf[i] * bf2f(kk[i]);
        }
    }

    s[0] *= SCALE;
    #pragma unroll
    for (int w = 0; w < 9; ++w) {
        const int lp = l + 2 * w - 8;
        s[1 + w] = (lp >= 0 && lp < L_) ? s[1 + w] * SCALE : -1e30f;
    }
    float m = s[0];
    #pragma unroll
    for (int w = 1; w < 10; ++w) m = fmaxf(m, s[w]);
    float sum = 0.f;
    #pragma unroll
    for (int w = 0; w < 10; ++w) { s[w] = __expf(s[w] - m); sum += s[w]; }
    const float rsum = 1.0f / sum;

    __syncthreads();
    #pragma unroll
    for (int i = 0; i < 9; ++i) {
        const int sl = i * 256 + t;
        if (sl < 272 * 8) {
            const int r = sl >> 3, c = sl & 7;
            const int lg = l0 - 8 + r;
            u16x8 v = {};
            if (lg >= 0 && lg < L_)
                v = *(const u16x8*)(qkvb + base + (size_t)(1 + lg) * QKV_COLS + 2 * E_ + hoff + c * 8);
            *(u16x8*)(kv + r * 64 + ((c ^ (r & 7)) * 8)) = v;
        }
    }
    __syncthreads();

    const size_t orow = (size_t)(b * S_ + 1 + l) * E_ + hoff;
    #pragma unroll
    for (int c = 0; c < 8; ++c) {
        float acc[8];
        #pragma unroll
        for (int i = 0; i < 8; ++i) acc[i] = s[0] * vc[c * 8 + i];
        #pragma unroll
        for (int w = 0; w < 9; ++w) {
            const int vr = t + 2 * w;
            const u16x8 vv = *(const u16x8*)(kv + vr * 64 + ((c ^ (vr & 7)) * 8));
            #pragma unroll
            for (int i = 0; i < 8; ++i) acc[i] += s[1 + w] * bf2f(vv[i]);
        }
        u16x8 o;
        #pragma unroll
        for (int i = 0; i < 8; ++i) o[i] = f2bf(acc[i] * rsum);
        *(u16x8*)(attnb + orow + c * 8) = o;
    }
}

// ---------------------------------------------------------------------------
// CLS stage 2: combine 33 chunks per (b,h). 16 blocks x 64 threads.
// ---------------------------------------------------------------------------
__global__ __launch_bounds__(64) void cls_attn_stage2(
    const float* __restrict__ part, u16* __restrict__ attnb)
{
    const int bh = blockIdx.x;
    const int lane = threadIdx.x;
    const int b = bh >> 3, h = bh & 7;
    float gm = -1e30f;
    for (int c = 0; c < NCHUNK2; ++c)
        gm = fmaxf(gm, part[((size_t)bh * NCHUNK2 + c) * 66]);
    float gl = 0.f, ga = 0.f;
    for (int c = 0; c < NCHUNK2; ++c) {
        const float* pp = part + ((size_t)bh * NCHUNK2 + c) * 66;
        const float w = __expf(pp[0] - gm);
        gl += pp[1] * w;
        ga += pp[2 + lane] * w;
    }
    attnb[(size_t)(b * S_) * E_ + h * D_ + lane] = f2bf(ga / gl);
}

// ---------------------------------------------------------------------------
// Launch
// ---------------------------------------------------------------------------
extern "C" void kernel_launch(void* const* d_in, const int* in_sizes, int n_in,
                              void* d_out, int out_size, void* d_ws, size_t ws_size,
                              hipStream_t stream)
{
    const float* x      = (const float*)d_in[0];
    const int*   coords = (const int*)  d_in[1];
    const float* w_qkv  = (const float*)d_in[2];
    const float* b_qkv  = (const float*)d_in[3];
    const float* w_out  = (const float*)d_in[4];
    const float* b_out  = (const float*)d_in[5];
    float* out = (float*)d_out;

    // workspace layout
    u16*   qkvb  = (u16*)d_ws;                                // M_ROWS x 1536 bf16
    u16*   attnb = qkvb + (size_t)M_ROWS * QKV_COLS;          // M_PAD x 512 bf16
    u16*   xb    = attnb + (size_t)M_PAD * E_;                // M_PAD x 512 bf16
    u16*   wqb   = xb + (size_t)M_PAD * E_;                   // 1536 x 512
    u16*   wob   = wqb + (size_t)QKV_COLS * E_;               // 512 x 512
    float* part  = (float*)(wob + (size_t)E_ * E_);           // PART_STRIDE floats
    float2* tab  = (float2*)(part + PART_STRIDE);             // B*L*32 float2 (4 MB)

    // 1. fused prep (x + weights to bf16, rope table, pad zero)
    prep_kernel<<<(PREP_TOTAL + 255) / 256, 256, 0, stream>>>(
        x, w_qkv, w_out, coords, xb, wqb, wob, tab, attnb);

    // 2. QKV projection + fused RoPE, 512-thread order-robust pipeline
    {
        dim3 grid(QKV_COLS / 128, M_PAD / 128);   // 12 x 129
        gemm512<1><<<grid, 512, 0, stream>>>(
            xb, wqb, b_qkv, qkvb, tab, M_ROWS, QKV_COLS);
    }

    // 3. merged CLS stage1 v2 + patch attention
    attn_fused<<<CLS_BLOCKS + PATCH_BLOCKS, 256, 0, stream>>>(qkvb, part, attnb);

    // 4. CLS stage 2
    cls_attn_stage2<<<B_ * H_, 64, 0, stream>>>(part, attnb);

    // 5. Output projection (fp32 out), same 512-thread pipeline
    {
        dim3 grid(E_ / 128, M_PAD / 128);         // 4 x 129
        gemm512<0><<<grid, 512, 0, stream>>>(
            attnb, wob, b_out, out, nullptr, M_ROWS, E_);
    }
}